// Round 7
// baseline (323.880 us; speedup 1.0000x reference)
//
#include <hip/hip_runtime.h>
#include <hip/hip_bf16.h>
#include <math.h>

#define D_MODEL 1024
#define SEQ     2048
#define BATCH   2
#define NHEAD   16
#define DKH     64
#define BH      (BATCH * NHEAD)   // 32

typedef unsigned short u16;
typedef unsigned int   u32;
typedef __bf16 bf16x8 __attribute__((ext_vector_type(8)));
typedef float  f32x4  __attribute__((ext_vector_type(4)));

#define MFMA16(a, b, c) __builtin_amdgcn_mfma_f32_16x16x32_bf16((a), (b), (c), 0, 0, 0)
#define AS1 __attribute__((address_space(1)))
#define AS3 __attribute__((address_space(3)))

__device__ __forceinline__ u16 f2bf(float x) {
    u32 u = __float_as_uint(x);
    u += 0x7fffu + ((u >> 16) & 1u);   // RNE (finite data)
    return (u16)(u >> 16);
}
__device__ __forceinline__ float bf2f(u16 b) {
    return __uint_as_float(((u32)b) << 16);
}
// async global->LDS, 16B/lane; lds dest wave-uniform (lane*16 implicit)
__device__ __forceinline__ void gl16(const u16* g, void* lds) {
    __builtin_amdgcn_global_load_lds((const AS1 u32*)g, (AS3 u32*)lds, 16, 0, 0);
}

// ---------------------------------------------------------------------------
// x fp32 -> hi/lo bf16
// ---------------------------------------------------------------------------
__global__ __launch_bounds__(256) void hilo_conv(
    const float* __restrict__ src, u16* __restrict__ hi, u16* __restrict__ lo, int n4)
{
    int i = blockIdx.x * 256 + threadIdx.x;
    if (i >= n4) return;
    float4 v = reinterpret_cast<const float4*>(src)[i];
    float a[4] = {v.x, v.y, v.z, v.w};
    u16 hh[4], ll[4];
    #pragma unroll
    for (int j = 0; j < 4; ++j) {
        u16 hb = f2bf(a[j]);
        hh[j] = hb;
        ll[j] = f2bf(a[j] - bf2f(hb));
    }
    uint2 H, L;
    H.x = hh[0] | ((u32)hh[1] << 16); H.y = hh[2] | ((u32)hh[3] << 16);
    L.x = ll[0] | ((u32)ll[1] << 16); L.y = ll[2] | ((u32)ll[3] << 16);
    reinterpret_cast<uint2*>(hi)[i] = H;
    reinterpret_cast<uint2*>(lo)[i] = L;
}

// ---------------------------------------------------------------------------
// W [K][N] fp32 -> WT hi/lo bf16 [N][K] (transpose + split). z selects matrix.
// ---------------------------------------------------------------------------
__global__ __launch_bounds__(256) void wt_conv(
    const float* __restrict__ W0, const float* __restrict__ W1,
    const float* __restrict__ W2, const float* __restrict__ W3,
    u16* __restrict__ H0, u16* __restrict__ L0, u16* __restrict__ H1, u16* __restrict__ L1,
    u16* __restrict__ H2, u16* __restrict__ L2, u16* __restrict__ H3, u16* __restrict__ L3)
{
    const float* W; u16 *Ht, *Lt;
    if (blockIdx.z == 0)      { W = W0; Ht = H0; Lt = L0; }
    else if (blockIdx.z == 1) { W = W1; Ht = H1; Lt = L1; }
    else if (blockIdx.z == 2) { W = W2; Ht = H2; Lt = L2; }
    else                      { W = W3; Ht = H3; Lt = L3; }

    __shared__ float T[64][65];
    const int n0 = blockIdx.x * 64, k0 = blockIdx.y * 64;
    const int t = threadIdx.x;
    #pragma unroll
    for (int i = 0; i < 4; ++i) {
        int f = t + i * 256;             // 0..1023 float4s
        int kr = f >> 4, ns = (f & 15) * 4;
        float4 v = *reinterpret_cast<const float4*>(&W[(size_t)(k0 + kr) * D_MODEL + n0 + ns]);
        T[kr][ns + 0] = v.x; T[kr][ns + 1] = v.y; T[kr][ns + 2] = v.z; T[kr][ns + 3] = v.w;
    }
    __syncthreads();
    #pragma unroll
    for (int i = 0; i < 4; ++i) {
        int f = t + i * 256;
        int nr = f >> 4, ks = (f & 15) * 4;
        u16 hh[4], ll[4];
        #pragma unroll
        for (int j = 0; j < 4; ++j) {
            float x = T[ks + j][nr];
            u16 hb = f2bf(x);
            hh[j] = hb;
            ll[j] = f2bf(x - bf2f(hb));
        }
        uint2 H, L;
        H.x = hh[0] | ((u32)hh[1] << 16); H.y = hh[2] | ((u32)hh[3] << 16);
        L.x = ll[0] | ((u32)ll[1] << 16); L.y = ll[2] | ((u32)ll[3] << 16);
        size_t o = (size_t)(n0 + nr) * D_MODEL + k0 + ks;
        *reinterpret_cast<uint2*>(&Ht[o]) = H;
        *reinterpret_cast<uint2*>(&Lt[o]) = L;
    }
}

// ---------------------------------------------------------------------------
// Fused QKV GEMM: 128x128 tile per block; A (x) staged ONCE per K-step,
// Bq/Bk/Bv all staged; 576 MFMA per block-iter on 64 KB staged = 147 FLOP/B.
// grid (8, 32) = 256 blocks = 1/CU. LDS 2 x 64 KB dbuf, prefetch dist 1.
// Outputs: Q,K -> hi/lo bf16; V -> flat bf16.
// ---------------------------------------------------------------------------
__global__ __launch_bounds__(256, 1) void gemm_qkv(
    const u16* __restrict__ AhG, const u16* __restrict__ AlG,
    const u16* __restrict__ Bqh, const u16* __restrict__ Bql,
    const u16* __restrict__ Bkh, const u16* __restrict__ Bkl,
    const u16* __restrict__ Bvh, const u16* __restrict__ Bvl,
    const float* __restrict__ bq, const float* __restrict__ bk, const float* __restrict__ bv,
    u16* __restrict__ Qh, u16* __restrict__ Ql,
    u16* __restrict__ Kh, u16* __restrict__ Kl, u16* __restrict__ Vb)
{
    constexpr int K = D_MODEL, N = D_MODEL;
    __shared__ u16 LB[2][32768];   // per buf: Ah|Al|Bqh|Bql|Bkh|Bkl|Bvh|Bvl x 8KB

    const int tid  = threadIdx.x;
    const int wv   = tid >> 6;
    const int lane = tid & 63;
    const int quad = lane >> 4;
    const int l16  = lane & 15;
    const int wm   = wv >> 1, wn = wv & 1;
    const int brow = blockIdx.y * 128, bcol = blockIdx.x * 128;

    // wave -> (hi ptr, lo ptr, row base): wave 0 stages A, waves 1..3 stage Bq/Bk/Bv
    const u16 *p0, *p1; int rbase;
    if (wv == 0)      { p0 = AhG; p1 = AlG; rbase = brow; }
    else if (wv == 1) { p0 = Bqh; p1 = Bql; rbase = bcol; }
    else if (wv == 2) { p0 = Bkh; p1 = Bkl; rbase = bcol; }
    else              { p0 = Bvh; p1 = Bvl; rbase = bcol; }
    // global seg swizzle: LDS seg (lane&3) holds global seg (lane&3)^((r>>1)&3);
    // r = cc*16 + (lane>>2) => (r>>1)&3 == (lane>>3)&3
    const size_t o0 = (size_t)(rbase + (lane >> 2)) * K + (size_t)(((lane & 3) ^ ((lane >> 3) & 3)) * 8);
    const int ldsw = wv * 16384;   // byte base of this wave's two arrays

    // fragment LDS byte offsets within an array (64-B rows, seg swizzle)
    int aro[4], bro[4];
    #pragma unroll
    for (int i = 0; i < 4; ++i) {
        int mr = wm * 64 + i * 16 + l16;
        aro[i] = mr * 64 + ((quad ^ ((mr >> 1) & 3)) * 16);
        int nr = wn * 64 + i * 16 + l16;
        bro[i] = nr * 64 + ((quad ^ ((nr >> 1) & 3)) * 16);
    }

    f32x4 acc[3][4][4] = {};

    // prefetch k0=0 into buffer 0 (16 chunks of 1 KB per wave)
    #pragma unroll
    for (int j = 0; j < 16; ++j) {
        const u16* p = (j < 8) ? p0 : p1;
        gl16(p + o0 + (size_t)(j & 7) * 16 * K,
             (char*)LB[0] + ldsw + (j >> 3) * 8192 + (j & 7) * 1024);
    }

    for (int it = 0; it < K / 32; ++it) {
        const int cur = it & 1;
        __syncthreads();   // vmcnt(0) drained: buf[cur] ready, prev compute done
        if (it + 1 < K / 32) {
            const int nxt = cur ^ 1;
            const size_t k1 = (size_t)(it + 1) * 32;
            #pragma unroll
            for (int j = 0; j < 16; ++j) {
                const u16* p = (j < 8) ? p0 : p1;
                gl16(p + o0 + (size_t)(j & 7) * 16 * K + k1,
                     (char*)LB[nxt] + ldsw + (j >> 3) * 8192 + (j & 7) * 1024);
            }
        }

        bf16x8 ah[4], al[4];
        #pragma unroll
        for (int i = 0; i < 4; ++i) {
            ah[i] = *reinterpret_cast<const bf16x8*>((const char*)LB[cur] + aro[i]);
            al[i] = *reinterpret_cast<const bf16x8*>((const char*)LB[cur] + 8192 + aro[i]);
        }
        #pragma unroll
        for (int m = 0; m < 3; ++m) {
            const int bb = 16384 + m * 16384;
            bf16x8 bh[4], bl[4];
            #pragma unroll
            for (int i = 0; i < 4; ++i) {
                bh[i] = *reinterpret_cast<const bf16x8*>((const char*)LB[cur] + bb + bro[i]);
                bl[i] = *reinterpret_cast<const bf16x8*>((const char*)LB[cur] + bb + 8192 + bro[i]);
            }
            #pragma unroll
            for (int mi = 0; mi < 4; ++mi)
                #pragma unroll
                for (int ni = 0; ni < 4; ++ni) {
                    f32x4 c = acc[m][mi][ni];
                    c = MFMA16(ah[mi], bh[ni], c);
                    c = MFMA16(ah[mi], bl[ni], c);
                    c = MFMA16(al[mi], bh[ni], c);
                    acc[m][mi][ni] = c;
                }
        }
    }

    // epilogue: Q,K hi/lo; V flat bf16
    #pragma unroll
    for (int m = 0; m < 3; ++m) {
        const float* bias = (m == 0) ? bq : (m == 1) ? bk : bv;
        #pragma unroll
        for (int mi = 0; mi < 4; ++mi) {
            #pragma unroll
            for (int ni = 0; ni < 4; ++ni) {
                int col = bcol + wn * 64 + ni * 16 + l16;
                float bvv = bias[col];
                #pragma unroll
                for (int r = 0; r < 4; ++r) {
                    int row = brow + wm * 64 + mi * 16 + quad * 4 + r;
                    size_t idx = (size_t)row * N + col;
                    float v = acc[m][mi][ni][r] + bvv;
                    if (m == 0) {
                        u16 h = f2bf(v);
                        Qh[idx] = h; Ql[idx] = f2bf(v - bf2f(h));
                    } else if (m == 1) {
                        u16 h = f2bf(v);
                        Kh[idx] = h; Kl[idx] = f2bf(v - bf2f(h));
                    } else {
                        Vb[idx] = f2bf(v);
                    }
                }
            }
        }
    }
}

// ---------------------------------------------------------------------------
// Split-bf16 MFMA GEMM (out-proj): C = A @ WT^T + bias, fp32 out.
// 128x128 tile, BK=32, dbuf prefetch (round-6 structure).
// ---------------------------------------------------------------------------
__global__ __launch_bounds__(256) void gemm_split(
    const u16* __restrict__ AhG, const u16* __restrict__ AlG,
    const u16* __restrict__ Bh, const u16* __restrict__ Bl,
    const float* __restrict__ bias, float* __restrict__ Cf, int M, int N, int K)
{
    __shared__ u16 AhS[2][128 * 32];
    __shared__ u16 AlS[2][128 * 32];
    __shared__ u16 BhS[2][128 * 32];
    __shared__ u16 BlS[2][128 * 32];

    const int tid  = threadIdx.x;
    const int wv   = tid >> 6;
    const int lane = tid & 63;
    const int quad = lane >> 4;
    const int l16  = lane & 15;
    const int wm   = wv >> 1, wn = wv & 1;
    const int brow = blockIdx.y * 128, bcol = blockIdx.x * 128;

    size_t aofs[2], bofs[2];
    int ldsb[2];
    #pragma unroll
    for (int j = 0; j < 2; ++j) {
        int c = wv * 2 + j;
        int r = c * 16 + (lane >> 2);
        int gseg = (lane & 3) ^ ((r >> 1) & 3);
        aofs[j] = (size_t)(brow + r) * K + gseg * 8;
        bofs[j] = (size_t)(bcol + r) * K + gseg * 8;
        ldsb[j] = c * 1024;
    }

    int aro[4], bro[4];
    #pragma unroll
    for (int i = 0; i < 4; ++i) {
        int mr = wm * 64 + i * 16 + l16;
        aro[i] = mr * 64 + ((quad ^ ((mr >> 1) & 3)) * 16);
        int nr = wn * 64 + i * 16 + l16;
        bro[i] = nr * 64 + ((quad ^ ((nr >> 1) & 3)) * 16);
    }

    f32x4 acc[4][4] = {};

    #pragma unroll
    for (int j = 0; j < 2; ++j) {
        gl16(AhG + aofs[j], (char*)AhS[0] + ldsb[j]);
        gl16(AlG + aofs[j], (char*)AlS[0] + ldsb[j]);
        gl16(Bh + bofs[j], (char*)BhS[0] + ldsb[j]);
        gl16(Bl + bofs[j], (char*)BlS[0] + ldsb[j]);
    }

    const int NIT = K / 32;
    for (int it = 0; it < NIT; ++it) {
        const int cur = it & 1;
        __syncthreads();
        if (it + 1 < NIT) {
            const int k1 = (it + 1) * 32;
            const int nxt = cur ^ 1;
            #pragma unroll
            for (int j = 0; j < 2; ++j) {
                gl16(AhG + aofs[j] + k1, (char*)AhS[nxt] + ldsb[j]);
                gl16(AlG + aofs[j] + k1, (char*)AlS[nxt] + ldsb[j]);
                gl16(Bh + bofs[j] + k1, (char*)BhS[nxt] + ldsb[j]);
                gl16(Bl + bofs[j] + k1, (char*)BlS[nxt] + ldsb[j]);
            }
        }

        bf16x8 ah[4], al[4], bh[4], bl[4];
        #pragma unroll
        for (int i = 0; i < 4; ++i) {
            ah[i] = *reinterpret_cast<const bf16x8*>((const char*)AhS[cur] + aro[i]);
            al[i] = *reinterpret_cast<const bf16x8*>((const char*)AlS[cur] + aro[i]);
            bh[i] = *reinterpret_cast<const bf16x8*>((const char*)BhS[cur] + bro[i]);
            bl[i] = *reinterpret_cast<const bf16x8*>((const char*)BlS[cur] + bro[i]);
        }
        #pragma unroll
        for (int mi = 0; mi < 4; ++mi)
            #pragma unroll
            for (int ni = 0; ni < 4; ++ni) {
                f32x4 c = acc[mi][ni];
                c = MFMA16(ah[mi], bh[ni], c);
                c = MFMA16(ah[mi], bl[ni], c);
                c = MFMA16(al[mi], bh[ni], c);
                acc[mi][ni] = c;
            }
    }

    #pragma unroll
    for (int mi = 0; mi < 4; ++mi) {
        #pragma unroll
        for (int ni = 0; ni < 4; ++ni) {
            int col = bcol + wn * 64 + ni * 16 + l16;
            float bvv = bias[col];
            #pragma unroll
            for (int r = 0; r < 4; ++r) {
                int row = brow + wm * 64 + mi * 16 + quad * 4 + r;
                Cf[(size_t)row * N + col] = acc[mi][ni][r] + bvv;
            }
        }
    }
}

// ---------------------------------------------------------------------------
// V bf16 flat [BH][SEQ][64] (contiguous reshape slabs) -> Vt bf16 [BH][64][SEQ]
// ---------------------------------------------------------------------------
__global__ __launch_bounds__(256) void v_transpose(
    const u16* __restrict__ V, u16* __restrict__ Vt)
{
    __shared__ u16 T[64][72];
    const int bh = blockIdx.y, st = blockIdx.x;
    const u16* src = V + ((size_t)bh * SEQ + (size_t)st * 64) * 64;
    const int t = threadIdx.x;
    #pragma unroll
    for (int i = 0; i < 2; ++i) {
        int c  = t + i * 256;
        int s  = c >> 3;
        int d0 = (c & 7) * 8;
        uint4 v = reinterpret_cast<const uint4*>(src)[c];
        u16 e[8];
        e[0] = (u16)(v.x & 0xffff); e[1] = (u16)(v.x >> 16);
        e[2] = (u16)(v.y & 0xffff); e[3] = (u16)(v.y >> 16);
        e[4] = (u16)(v.z & 0xffff); e[5] = (u16)(v.z >> 16);
        e[6] = (u16)(v.w & 0xffff); e[7] = (u16)(v.w >> 16);
        #pragma unroll
        for (int j = 0; j < 8; ++j) T[d0 + j][s] = e[j];
    }
    __syncthreads();
    const int d = t >> 2, seg = t & 3;
    u16* dst = Vt + (size_t)bh * 64 * SEQ + (size_t)d * SEQ + st * 64 + seg * 16;
    uint4 a = *reinterpret_cast<const uint4*>(&T[d][seg * 16]);
    uint4 b = *reinterpret_cast<const uint4*>(&T[d][seg * 16 + 8]);
    reinterpret_cast<uint4*>(dst)[0] = a;
    reinterpret_cast<uint4*>(dst)[1] = b;
}

// ---------------------------------------------------------------------------
// MFMA flash attention, no-max softmax, 256-query tile (4 subs/wave).
// grid (8, 32) = 256 blocks = 1/CU. K/V dbuf + prefetch; 1 barrier/iter.
// LDS: K/V 2x24 KB + Pb 36 KB = 84 KB.
// ---------------------------------------------------------------------------
__global__ __launch_bounds__(256, 1) void attn_mfma(
    const u16* __restrict__ Qh_g, const u16* __restrict__ Ql_g,
    const u16* __restrict__ Kh_g, const u16* __restrict__ Kl_g,
    const u16* __restrict__ Vt_g, u16* __restrict__ Ch_g, u16* __restrict__ Cl_g)
{
    __shared__ u16 KhS[2][64 * 64];
    __shared__ u16 KlS[2][64 * 64];
    __shared__ u16 VtS[2][64 * 64];
    __shared__ u16 Pb [256 * 72];

    const int tid  = threadIdx.x;
    const int wv   = tid >> 6;
    const int lane = tid & 63;
    const int quad = lane >> 4;
    const int l16  = lane & 15;
    const int bh   = blockIdx.y;
    const int qt   = blockIdx.x;

    const size_t qbase = ((size_t)bh * SEQ + (size_t)qt * 256) * 64;
    const size_t kbh   = (size_t)bh * SEQ * 64;
    const size_t vtbh  = (size_t)bh * 64 * SEQ;

    // ---- Q fragments: direct global -> VGPR (64 q-rows per wave) ----
    bf16x8 qf[4][2][2];   // [sub][ks][hi/lo]
    #pragma unroll
    for (int sub = 0; sub < 4; ++sub)
        #pragma unroll
        for (int ks = 0; ks < 2; ++ks) {
            size_t o = qbase + (size_t)(wv * 64 + sub * 16 + l16) * 64 + ks * 32 + quad * 8;
            qf[sub][ks][0] = *reinterpret_cast<const bf16x8*>(Qh_g + o);
            qf[sub][ks][1] = *reinterpret_cast<const bf16x8*>(Ql_g + o);
        }

    // K/V staging addresses; chunk c = wv*2 + j (8 rows each)
    size_t kofs[2], vofs[2];
    int ldsb[2];
    #pragma unroll
    for (int j = 0; j < 2; ++j) {
        int c   = wv * 2 + j;
        int row = c * 8 + (lane >> 3);
        int sg  = (lane & 7) ^ (row & 7);
        kofs[j] = kbh  + (size_t)row * 64 + sg * 8;
        vofs[j] = vtbh + (size_t)row * SEQ + sg * 8;
        ldsb[j] = c * 1024;
    }

    // fragment LDS byte offsets: row = t*16 + l16; swizzle = (ks*4+quad)^(l16&7)
    int fro[4][2];
    #pragma unroll
    for (int t = 0; t < 4; ++t)
        #pragma unroll
        for (int ks = 0; ks < 2; ++ks)
            fro[t][ks] = (t * 16 + l16) * 128 + (((ks * 4 + quad) ^ (l16 & 7)) * 16);

    f32x4 oacc[4][4] = {};
    float psum[4][4] = {};

    // prefetch kt = 0 into buffer 0
    #pragma unroll
    for (int j = 0; j < 2; ++j) {
        gl16(Kh_g + kofs[j], (char*)KhS[0] + ldsb[j]);
        gl16(Kl_g + kofs[j], (char*)KlS[0] + ldsb[j]);
        gl16(Vt_g + vofs[j], (char*)VtS[0] + ldsb[j]);
    }

    for (int kt = 0; kt < SEQ / 64; ++kt) {
        const int cur = kt & 1;
        __syncthreads();
        if (kt + 1 < SEQ / 64) {
            const int nxt = cur ^ 1;
            #pragma unroll
            for (int j = 0; j < 2; ++j) {
                size_t ko = kofs[j] + (size_t)(kt + 1) * 64 * 64;
                gl16(Kh_g + ko, (char*)KhS[nxt] + ldsb[j]);
                gl16(Kl_g + ko, (char*)KlS[nxt] + ldsb[j]);
                gl16(Vt_g + vofs[j] + (kt + 1) * 64, (char*)VtS[nxt] + ldsb[j]);
            }
        }

        // ---- S = Q K^T (3-term split) ----
        f32x4 sacc[4][4] = {};   // [sub][t4]
        #pragma unroll
        for (int t4 = 0; t4 < 4; ++t4) {
            bf16x8 kh[2], kl[2];
            #pragma unroll
            for (int ks = 0; ks < 2; ++ks) {
                kh[ks] = *reinterpret_cast<const bf16x8*>((const char*)KhS[cur] + fro[t4][ks]);
                kl[ks] = *reinterpret_cast<const bf16x8*>((const char*)KlS[cur] + fro[t4][ks]);
            }
            #pragma unroll
            for (int sub = 0; sub < 4; ++sub) {
                f32x4 a = sacc[sub][t4];
                a = MFMA16(qf[sub][0][0], kh[0], a);
                a = MFMA16(qf[sub][0][0], kl[0], a);
                a = MFMA16(qf[sub][0][1], kh[0], a);
                a = MFMA16(qf[sub][1][0], kh[1], a);
                a = MFMA16(qf[sub][1][0], kl[1], a);
                a = MFMA16(qf[sub][1][1], kh[1], a);
                sacc[sub][t4] = a;
            }
        }

        // ---- p = exp(s/8 - 11.09); uniform shift cancels in normalization ----
        #pragma unroll
        for (int sub = 0; sub < 4; ++sub) {
            int rowb = wv * 64 + sub * 16 + quad * 4;
            #pragma unroll
            for (int r = 0; r < 4; ++r) {
                float p0 = __expf(fmaf(sacc[sub][0][r], 0.125f, -11.0903549f));
                float p1 = __expf(fmaf(sacc[sub][1][r], 0.125f, -11.0903549f));
                float p2 = __expf(fmaf(sacc[sub][2][r], 0.125f, -11.0903549f));
                float p3 = __expf(fmaf(sacc[sub][3][r], 0.125f, -11.0903549f));
                psum[sub][r] += (p0 + p1) + (p2 + p3);
                int ro = (rowb + r) * 72 + l16;
                Pb[ro +  0] = f2bf(p0);
                Pb[ro + 16] = f2bf(p1);
                Pb[ro + 32] = f2bf(p2);
                Pb[ro + 48] = f2bf(p3);
            }
        }
        // Pb rows are wave-private: lgkmcnt ordering only, no barrier.

        // ---- O += P @ V ----
        bf16x8 bv[4][2];
        #pragma unroll
        for (int dt = 0; dt < 4; ++dt)
            #pragma unroll
            for (int ks = 0; ks < 2; ++ks)
                bv[dt][ks] = *reinterpret_cast<const bf16x8*>((const char*)VtS[cur] + fro[dt][ks]);
        #pragma unroll
        for (int sub = 0; sub < 4; ++sub) {
            bf16x8 ap[2];
            #pragma unroll
            for (int ks = 0; ks < 2; ++ks)
                ap[ks] = *reinterpret_cast<const bf16x8*>(
                    &Pb[(wv * 64 + sub * 16 + l16) * 72 + ks * 32 + quad * 8]);
            #pragma unroll
            for (int dt = 0; dt < 4; ++dt) {
                oacc[sub][dt] = MFMA16(ap[0], bv[dt][0], oacc[sub][dt]);
                oacc[sub][dt] = MFMA16(ap[1], bv[dt][1], oacc[sub][dt]);
            }
        }
    }

    // ---- row-sum reduction across the 16 k-lanes (once) ----
    #pragma unroll
    for (int sub = 0; sub < 4; ++sub)
        #pragma unroll
        for (int r = 0; r < 4; ++r) {
            float s = psum[sub][r];
            s += __shfl_xor(s, 1, 64);
            s += __shfl_xor(s, 2, 64);
            s += __shfl_xor(s, 4, 64);
            s += __shfl_xor(s, 8, 64);
            psum[sub][r] = s;
        }

    // ---- epilogue: normalize, split to hi/lo bf16 ctx ----
    u16* Oh = Ch_g + qbase;
    u16* Ol = Cl_g + qbase;
    #pragma unroll
    for (int sub = 0; sub < 4; ++sub) {
        float inv[4];
        #pragma unroll
        for (int r = 0; r < 4; ++r) inv[r] = 1.0f / psum[sub][r];
        #pragma unroll
        for (int dt = 0; dt < 4; ++dt)
            #pragma unroll
            for (int r = 0; r < 4; ++r) {
                int row = wv * 64 + sub * 16 + quad * 4 + r;
                float v = oacc[sub][dt][r] * inv[r];
                u16 h = f2bf(v);
                size_t idx = (size_t)row * 64 + dt * 16 + l16;
                Oh[idx] = h;
                Ol[idx] = f2bf(v - bf2f(h));
            }
    }
}

// ---------------------------------------------------------------------------
extern "C" void kernel_launch(void* const* d_in, const int* in_sizes, int n_in,
                              void* d_out, int out_size, void* d_ws, size_t ws_size,
                              hipStream_t stream)
{
    const float* x  = (const float*)d_in[0];
    const float* Wq = (const float*)d_in[1];
    const float* bq = (const float*)d_in[2];
    const float* Wk = (const float*)d_in[3];
    const float* bk = (const float*)d_in[4];
    const float* Wv = (const float*)d_in[5];
    const float* bv = (const float*)d_in[6];
    const float* Wo = (const float*)d_in[7];
    const float* bo = (const float*)d_in[8];
    float* out = (float*)d_out;

    const int M = BATCH * SEQ;        // 4096
    const int N = D_MODEL;            // 1024
    const int K = D_MODEL;            // 1024
    const size_t NE = (size_t)M * N;  // 4,194,304
    const size_t NW = (size_t)N * K;  // 1,048,576

    u16* w16 = (u16*)d_ws;
    u16* Xh   = w16;
    u16* Xl   = Xh   + NE;
    u16* Qh   = Xl   + NE;
    u16* Ql   = Qh   + NE;
    u16* Kh   = Ql   + NE;
    u16* Kl   = Kh   + NE;
    u16* Ctxh = Kl   + NE;
    u16* Ctxl = Ctxh + NE;
    u16* Vtb  = Ctxl + NE;
    u16* Vb16 = Vtb  + NE;
    u16* WTqh = Vb16 + NE;
    u16* WTql = WTqh + NW;
    u16* WTkh = WTql + NW;
    u16* WTkl = WTkh + NW;
    u16* WTvh = WTkl + NW;
    u16* WTvl = WTvh + NW;
    u16* WToh = WTvl + NW;
    u16* WTol = WToh + NW;

    dim3 blk(256);

    // input conversions
    hilo_conv<<<dim3((int)(NE / 4 / 256)), blk, 0, stream>>>(x, Xh, Xl, (int)(NE / 4));
    wt_conv<<<dim3(16, 16, 4), blk, 0, stream>>>(
        Wq, Wk, Wv, Wo, WTqh, WTql, WTkh, WTkl, WTvh, WTvl, WToh, WTol);

    // fused QKV projection: A staged once; Q,K -> hi/lo; V -> flat bf16
    gemm_qkv<<<dim3(N / 128, M / 128), blk, 0, stream>>>(
        Xh, Xl, WTqh, WTql, WTkh, WTkl, WTvh, WTvl,
        bq, bk, bv, Qh, Ql, Kh, Kl, Vb16);

    // transpose V per contiguous reshape slab (bf16 in, bf16 out)
    v_transpose<<<dim3(SEQ / 64, BH), blk, 0, stream>>>(Vb16, Vtb);

    // attention (256-q tile) -> ctx hi/lo
    attn_mfma<<<dim3(SEQ / 256, BH), blk, 0, stream>>>(Qh, Ql, Kh, Kl, Vtb, Ctxh, Ctxl);

    // output projection
    gemm_split<<<dim3(N / 128, M / 128), blk, 0, stream>>>(
        Ctxh, Ctxl, WToh, WTol, bo, out, M, N, K);
}

// Round 8
// 290.545 us; speedup vs baseline: 1.1147x; 1.1147x over previous
//
#include <hip/hip_runtime.h>
#include <hip/hip_bf16.h>
#include <math.h>

#define D_MODEL 1024
#define SEQ     2048
#define BATCH   2
#define NHEAD   16
#define DKH     64
#define BH      (BATCH * NHEAD)   // 32

typedef unsigned short u16;
typedef unsigned int   u32;
typedef __bf16 bf16x8 __attribute__((ext_vector_type(8)));
typedef float  f32x4  __attribute__((ext_vector_type(4)));

#define MFMA16(a, b, c) __builtin_amdgcn_mfma_f32_16x16x32_bf16((a), (b), (c), 0, 0, 0)
#define AS1 __attribute__((address_space(1)))
#define AS3 __attribute__((address_space(3)))

__device__ __forceinline__ u16 f2bf(float x) {
    u32 u = __float_as_uint(x);
    u += 0x7fffu + ((u >> 16) & 1u);   // RNE (finite data)
    return (u16)(u >> 16);
}
__device__ __forceinline__ float bf2f(u16 b) {
    return __uint_as_float(((u32)b) << 16);
}
// async global->LDS, 16B/lane; lds dest wave-uniform (lane*16 implicit)
__device__ __forceinline__ void gl16(const u16* g, void* lds) {
    __builtin_amdgcn_global_load_lds((const AS1 u32*)g, (AS3 u32*)lds, 16, 0, 0);
}

// ---------------------------------------------------------------------------
// Combined conversions in one launch:
//   blocks [0, 4096)    : x fp32 -> hi/lo bf16
//   blocks [4096, 5120) : W [K][N] fp32 -> WT hi/lo bf16 [N][K] (4 matrices)
// ---------------------------------------------------------------------------
__global__ __launch_bounds__(256) void conv_all(
    const float* __restrict__ x, u16* __restrict__ Xh, u16* __restrict__ Xl, int n4,
    const float* __restrict__ W0, const float* __restrict__ W1,
    const float* __restrict__ W2, const float* __restrict__ W3,
    u16* __restrict__ H0, u16* __restrict__ L0, u16* __restrict__ H1, u16* __restrict__ L1,
    u16* __restrict__ H2, u16* __restrict__ L2, u16* __restrict__ H3, u16* __restrict__ L3)
{
    const int t = threadIdx.x;
    if ((int)blockIdx.x < 4096) {
        int i = blockIdx.x * 256 + t;
        if (i >= n4) return;
        float4 v = reinterpret_cast<const float4*>(x)[i];
        float a[4] = {v.x, v.y, v.z, v.w};
        u16 hh[4], ll[4];
        #pragma unroll
        for (int j = 0; j < 4; ++j) {
            u16 hb = f2bf(a[j]);
            hh[j] = hb;
            ll[j] = f2bf(a[j] - bf2f(hb));
        }
        uint2 H, L;
        H.x = hh[0] | ((u32)hh[1] << 16); H.y = hh[2] | ((u32)hh[3] << 16);
        L.x = ll[0] | ((u32)ll[1] << 16); L.y = ll[2] | ((u32)ll[3] << 16);
        reinterpret_cast<uint2*>(Xh)[i] = H;
        reinterpret_cast<uint2*>(Xl)[i] = L;
        return;
    }
    // ---- weight transpose+split ----
    int id = blockIdx.x - 4096;          // 0..1023
    int bx = id & 15, by = (id >> 4) & 15, bz = id >> 8;
    const float* W; u16 *Ht, *Lt;
    if (bz == 0)      { W = W0; Ht = H0; Lt = L0; }
    else if (bz == 1) { W = W1; Ht = H1; Lt = L1; }
    else if (bz == 2) { W = W2; Ht = H2; Lt = L2; }
    else              { W = W3; Ht = H3; Lt = L3; }

    __shared__ float T[64][65];
    const int n0 = bx * 64, k0 = by * 64;
    #pragma unroll
    for (int i = 0; i < 4; ++i) {
        int f = t + i * 256;             // 0..1023 float4s
        int kr = f >> 4, ns = (f & 15) * 4;
        float4 v = *reinterpret_cast<const float4*>(&W[(size_t)(k0 + kr) * D_MODEL + n0 + ns]);
        T[kr][ns + 0] = v.x; T[kr][ns + 1] = v.y; T[kr][ns + 2] = v.z; T[kr][ns + 3] = v.w;
    }
    __syncthreads();
    #pragma unroll
    for (int i = 0; i < 4; ++i) {
        int f = t + i * 256;
        int nr = f >> 4, ks = (f & 15) * 4;
        u16 hh[4], ll[4];
        #pragma unroll
        for (int j = 0; j < 4; ++j) {
            float xv = T[ks + j][nr];
            u16 hb = f2bf(xv);
            hh[j] = hb;
            ll[j] = f2bf(xv - bf2f(hb));
        }
        uint2 H, L;
        H.x = hh[0] | ((u32)hh[1] << 16); H.y = hh[2] | ((u32)hh[3] << 16);
        L.x = ll[0] | ((u32)ll[1] << 16); L.y = ll[2] | ((u32)ll[3] << 16);
        size_t o = (size_t)(n0 + nr) * D_MODEL + k0 + ks;
        *reinterpret_cast<uint2*>(&Ht[o]) = H;
        *reinterpret_cast<uint2*>(&Lt[o]) = L;
    }
}

// ---------------------------------------------------------------------------
// Fused QKV GEMM, 512 threads (8 waves, 2/SIMD): 128x128 tile; A staged once,
// Bq/Bk/Bv staged; wave tile 32x64. Each wave DMAs one 8 KB LDS sub-array.
// LDS 2 x 64 KB dbuf, prefetch dist 1. grid (8,32) = 256 = 1 block/CU.
// Outputs: Q,K -> hi/lo bf16; V -> flat bf16.
// ---------------------------------------------------------------------------
__global__ __launch_bounds__(512, 2) void gemm_qkv(
    const u16* __restrict__ AhG, const u16* __restrict__ AlG,
    const u16* __restrict__ Bqh, const u16* __restrict__ Bql,
    const u16* __restrict__ Bkh, const u16* __restrict__ Bkl,
    const u16* __restrict__ Bvh, const u16* __restrict__ Bvl,
    const float* __restrict__ bq, const float* __restrict__ bk, const float* __restrict__ bv,
    u16* __restrict__ Qh, u16* __restrict__ Ql,
    u16* __restrict__ Kh, u16* __restrict__ Kl, u16* __restrict__ Vb)
{
    constexpr int K = D_MODEL, N = D_MODEL;
    __shared__ u16 LB[2][32768];   // per buf: Ah|Al|Bqh|Bql|Bkh|Bkl|Bvh|Bvl x 8KB

    const int tid  = threadIdx.x;
    const int wv   = tid >> 6;          // 0..7
    const int lane = tid & 63;
    const int quad = lane >> 4;
    const int l16  = lane & 15;
    const int wm   = wv >> 1, wn = wv & 1;   // 4 x 2 wave grid; wave tile 32x64
    const int brow = blockIdx.y * 128, bcol = blockIdx.x * 128;

    // wave -> staged array
    const u16* p;
    if (wv == 0)      p = AhG;
    else if (wv == 1) p = AlG;
    else if (wv == 2) p = Bqh;
    else if (wv == 3) p = Bql;
    else if (wv == 4) p = Bkh;
    else if (wv == 5) p = Bkl;
    else if (wv == 6) p = Bvh;
    else              p = Bvl;
    const int rbase = (wv < 2) ? brow : bcol;
    // seg swizzle: LDS seg (lane&3) holds global seg (lane&3)^((r>>1)&3);
    // r = j*16 + (lane>>2) => (r>>1)&3 == (lane>>3)&3 (j*16 contributes 0 mod 4)
    const size_t o0 = (size_t)(rbase + (lane >> 2)) * K
                    + (size_t)(((lane & 3) ^ ((lane >> 3) & 3)) * 8);
    const int ldsw = wv * 8192;     // byte base of this wave's sub-array

    // fragment LDS byte offsets within a sub-array (64-B rows, seg swizzle)
    int aro[2], bro[4];
    #pragma unroll
    for (int i = 0; i < 2; ++i) {
        int mr = wm * 32 + i * 16 + l16;
        aro[i] = mr * 64 + ((quad ^ ((mr >> 1) & 3)) * 16);
    }
    #pragma unroll
    for (int i = 0; i < 4; ++i) {
        int nr = wn * 64 + i * 16 + l16;
        bro[i] = nr * 64 + ((quad ^ ((nr >> 1) & 3)) * 16);
    }

    f32x4 acc[3][2][4] = {};

    // prefetch k=0 into buffer 0 (8 chunks of 1 KB per wave)
    #pragma unroll
    for (int j = 0; j < 8; ++j)
        gl16(p + o0 + (size_t)j * 16 * K, (char*)LB[0] + ldsw + j * 1024);

    for (int it = 0; it < K / 32; ++it) {
        const int cur = it & 1;
        __syncthreads();   // vmcnt drained: buf[cur] ready, prev compute done
        if (it + 1 < K / 32) {
            const int nxt = cur ^ 1;
            const size_t k1 = (size_t)(it + 1) * 32;
            #pragma unroll
            for (int j = 0; j < 8; ++j)
                gl16(p + o0 + (size_t)j * 16 * K + k1, (char*)LB[nxt] + ldsw + j * 1024);
        }

        bf16x8 ah[2], al[2];
        #pragma unroll
        for (int i = 0; i < 2; ++i) {
            ah[i] = *reinterpret_cast<const bf16x8*>((const char*)LB[cur] + aro[i]);
            al[i] = *reinterpret_cast<const bf16x8*>((const char*)LB[cur] + 8192 + aro[i]);
        }
        #pragma unroll
        for (int m = 0; m < 3; ++m) {
            const int bb = 16384 + m * 16384;
            bf16x8 bh[4], bl[4];
            #pragma unroll
            for (int i = 0; i < 4; ++i) {
                bh[i] = *reinterpret_cast<const bf16x8*>((const char*)LB[cur] + bb + bro[i]);
                bl[i] = *reinterpret_cast<const bf16x8*>((const char*)LB[cur] + bb + 8192 + bro[i]);
            }
            #pragma unroll
            for (int mi = 0; mi < 2; ++mi)
                #pragma unroll
                for (int ni = 0; ni < 4; ++ni) {
                    f32x4 c = acc[m][mi][ni];
                    c = MFMA16(ah[mi], bh[ni], c);
                    c = MFMA16(ah[mi], bl[ni], c);
                    c = MFMA16(al[mi], bh[ni], c);
                    acc[m][mi][ni] = c;
                }
        }
    }

    // epilogue: Q,K hi/lo; V flat bf16
    #pragma unroll
    for (int m = 0; m < 3; ++m) {
        const float* bias = (m == 0) ? bq : (m == 1) ? bk : bv;
        #pragma unroll
        for (int mi = 0; mi < 2; ++mi) {
            #pragma unroll
            for (int ni = 0; ni < 4; ++ni) {
                int col = bcol + wn * 64 + ni * 16 + l16;
                float bvv = bias[col];
                #pragma unroll
                for (int r = 0; r < 4; ++r) {
                    int row = brow + wm * 32 + mi * 16 + quad * 4 + r;
                    size_t idx = (size_t)row * N + col;
                    float v = acc[m][mi][ni][r] + bvv;
                    if (m == 0) {
                        u16 h = f2bf(v);
                        Qh[idx] = h; Ql[idx] = f2bf(v - bf2f(h));
                    } else if (m == 1) {
                        u16 h = f2bf(v);
                        Kh[idx] = h; Kl[idx] = f2bf(v - bf2f(h));
                    } else {
                        Vb[idx] = f2bf(v);
                    }
                }
            }
        }
    }
}

// ---------------------------------------------------------------------------
// Split-bf16 MFMA GEMM (out-proj): C = A @ WT^T + bias, fp32 out.
// 128x128 tile, BK=32, dbuf prefetch; 256 threads, 2 blocks/CU.
// ---------------------------------------------------------------------------
__global__ __launch_bounds__(256) void gemm_split(
    const u16* __restrict__ AhG, const u16* __restrict__ AlG,
    const u16* __restrict__ Bh, const u16* __restrict__ Bl,
    const float* __restrict__ bias, float* __restrict__ Cf, int M, int N, int K)
{
    __shared__ u16 AhS[2][128 * 32];
    __shared__ u16 AlS[2][128 * 32];
    __shared__ u16 BhS[2][128 * 32];
    __shared__ u16 BlS[2][128 * 32];

    const int tid  = threadIdx.x;
    const int wv   = tid >> 6;
    const int lane = tid & 63;
    const int quad = lane >> 4;
    const int l16  = lane & 15;
    const int wm   = wv >> 1, wn = wv & 1;
    const int brow = blockIdx.y * 128, bcol = blockIdx.x * 128;

    size_t aofs[2], bofs[2];
    int ldsb[2];
    #pragma unroll
    for (int j = 0; j < 2; ++j) {
        int c = wv * 2 + j;
        int r = c * 16 + (lane >> 2);
        int gseg = (lane & 3) ^ ((r >> 1) & 3);
        aofs[j] = (size_t)(brow + r) * K + gseg * 8;
        bofs[j] = (size_t)(bcol + r) * K + gseg * 8;
        ldsb[j] = c * 1024;
    }

    int aro[4], bro[4];
    #pragma unroll
    for (int i = 0; i < 4; ++i) {
        int mr = wm * 64 + i * 16 + l16;
        aro[i] = mr * 64 + ((quad ^ ((mr >> 1) & 3)) * 16);
        int nr = wn * 64 + i * 16 + l16;
        bro[i] = nr * 64 + ((quad ^ ((nr >> 1) & 3)) * 16);
    }

    f32x4 acc[4][4] = {};

    #pragma unroll
    for (int j = 0; j < 2; ++j) {
        gl16(AhG + aofs[j], (char*)AhS[0] + ldsb[j]);
        gl16(AlG + aofs[j], (char*)AlS[0] + ldsb[j]);
        gl16(Bh + bofs[j], (char*)BhS[0] + ldsb[j]);
        gl16(Bl + bofs[j], (char*)BlS[0] + ldsb[j]);
    }

    const int NIT = K / 32;
    for (int it = 0; it < NIT; ++it) {
        const int cur = it & 1;
        __syncthreads();
        if (it + 1 < NIT) {
            const int k1 = (it + 1) * 32;
            const int nxt = cur ^ 1;
            #pragma unroll
            for (int j = 0; j < 2; ++j) {
                gl16(AhG + aofs[j] + k1, (char*)AhS[nxt] + ldsb[j]);
                gl16(AlG + aofs[j] + k1, (char*)AlS[nxt] + ldsb[j]);
                gl16(Bh + bofs[j] + k1, (char*)BhS[nxt] + ldsb[j]);
                gl16(Bl + bofs[j] + k1, (char*)BlS[nxt] + ldsb[j]);
            }
        }

        bf16x8 ah[4], al[4], bh[4], bl[4];
        #pragma unroll
        for (int i = 0; i < 4; ++i) {
            ah[i] = *reinterpret_cast<const bf16x8*>((const char*)AhS[cur] + aro[i]);
            al[i] = *reinterpret_cast<const bf16x8*>((const char*)AlS[cur] + aro[i]);
            bh[i] = *reinterpret_cast<const bf16x8*>((const char*)BhS[cur] + bro[i]);
            bl[i] = *reinterpret_cast<const bf16x8*>((const char*)BlS[cur] + bro[i]);
        }
        #pragma unroll
        for (int mi = 0; mi < 4; ++mi)
            #pragma unroll
            for (int ni = 0; ni < 4; ++ni) {
                f32x4 c = acc[mi][ni];
                c = MFMA16(ah[mi], bh[ni], c);
                c = MFMA16(ah[mi], bl[ni], c);
                c = MFMA16(al[mi], bh[ni], c);
                acc[mi][ni] = c;
            }
    }

    #pragma unroll
    for (int mi = 0; mi < 4; ++mi) {
        #pragma unroll
        for (int ni = 0; ni < 4; ++ni) {
            int col = bcol + wn * 64 + ni * 16 + l16;
            float bvv = bias[col];
            #pragma unroll
            for (int r = 0; r < 4; ++r) {
                int row = brow + wm * 64 + mi * 16 + quad * 4 + r;
                Cf[(size_t)row * N + col] = acc[mi][ni][r] + bvv;
            }
        }
    }
}

// ---------------------------------------------------------------------------
// V bf16 flat [BH][SEQ][64] (contiguous reshape slabs) -> Vt bf16 [BH][64][SEQ]
// ---------------------------------------------------------------------------
__global__ __launch_bounds__(256) void v_transpose(
    const u16* __restrict__ V, u16* __restrict__ Vt)
{
    __shared__ u16 T[64][72];
    const int bh = blockIdx.y, st = blockIdx.x;
    const u16* src = V + ((size_t)bh * SEQ + (size_t)st * 64) * 64;
    const int t = threadIdx.x;
    #pragma unroll
    for (int i = 0; i < 2; ++i) {
        int c  = t + i * 256;
        int s  = c >> 3;
        int d0 = (c & 7) * 8;
        uint4 v = reinterpret_cast<const uint4*>(src)[c];
        u16 e[8];
        e[0] = (u16)(v.x & 0xffff); e[1] = (u16)(v.x >> 16);
        e[2] = (u16)(v.y & 0xffff); e[3] = (u16)(v.y >> 16);
        e[4] = (u16)(v.z & 0xffff); e[5] = (u16)(v.z >> 16);
        e[6] = (u16)(v.w & 0xffff); e[7] = (u16)(v.w >> 16);
        #pragma unroll
        for (int j = 0; j < 8; ++j) T[d0 + j][s] = e[j];
    }
    __syncthreads();
    const int d = t >> 2, seg = t & 3;
    u16* dst = Vt + (size_t)bh * 64 * SEQ + (size_t)d * SEQ + st * 64 + seg * 16;
    uint4 a = *reinterpret_cast<const uint4*>(&T[d][seg * 16]);
    uint4 b = *reinterpret_cast<const uint4*>(&T[d][seg * 16 + 8]);
    reinterpret_cast<uint4*>(dst)[0] = a;
    reinterpret_cast<uint4*>(dst)[1] = b;
}

// ---------------------------------------------------------------------------
// MFMA flash attention, 512 threads (8 waves, 2/SIMD), 256-q tile,
// 32 q-rows per wave. No-max softmax with TRUNCATED bf16 P; psum accumulates
// the truncated values so normalization cancels truncation bias exactly.
// K/V dbuf + prefetch dist 1; one barrier per k-tile.
// LDS: KVS 2 x 24 KB + Pb 36 KB = 84 KB -> 1 block/CU, 8 waves.
// ---------------------------------------------------------------------------
__global__ __launch_bounds__(512, 2) void attn_mfma(
    const u16* __restrict__ Qh_g, const u16* __restrict__ Ql_g,
    const u16* __restrict__ Kh_g, const u16* __restrict__ Kl_g,
    const u16* __restrict__ Vt_g, u16* __restrict__ Ch_g, u16* __restrict__ Cl_g)
{
    __shared__ u16 KVS[2][12288];   // per buf: Kh(8KB) | Kl(8KB) | Vt(8KB)
    __shared__ u16 Pb [256 * 72];

    const int tid  = threadIdx.x;
    const int wv   = tid >> 6;          // 0..7
    const int lane = tid & 63;
    const int quad = lane >> 4;
    const int l16  = lane & 15;
    const int bh   = blockIdx.y;
    const int qt   = blockIdx.x;

    const size_t qbase = ((size_t)bh * SEQ + (size_t)qt * 256) * 64;
    const size_t kbh   = (size_t)bh * SEQ * 64;
    const size_t vtbh  = (size_t)bh * 64 * SEQ;

    // ---- Q fragments: direct global -> VGPR (32 q-rows per wave) ----
    bf16x8 qf[2][2][2];   // [sub][ks][hi/lo]
    #pragma unroll
    for (int sub = 0; sub < 2; ++sub)
        #pragma unroll
        for (int ks = 0; ks < 2; ++ks) {
            size_t o = qbase + (size_t)(wv * 32 + sub * 16 + l16) * 64 + ks * 32 + quad * 8;
            qf[sub][ks][0] = *reinterpret_cast<const bf16x8*>(Qh_g + o);
            qf[sub][ks][1] = *reinterpret_cast<const bf16x8*>(Ql_g + o);
        }

    // K/V staging: 24 chunks of 1 KB (Kh 0-7, Kl 8-15, Vt 16-23); 3 per wave
    const u16* sp[3];
    size_t sofs[3], sstep[3];
    int sldb[3];
    #pragma unroll
    for (int j = 0; j < 3; ++j) {
        int c   = wv * 3 + j;            // 0..23
        int arr = c >> 3, cc = c & 7;
        int row = cc * 8 + (lane >> 3);
        int sg  = (lane & 7) ^ (row & 7);
        if (arr == 0)      { sp[j] = Kh_g; sofs[j] = kbh + (size_t)row * 64 + sg * 8;  sstep[j] = 4096; }
        else if (arr == 1) { sp[j] = Kl_g; sofs[j] = kbh + (size_t)row * 64 + sg * 8;  sstep[j] = 4096; }
        else               { sp[j] = Vt_g; sofs[j] = vtbh + (size_t)row * SEQ + sg * 8; sstep[j] = 64; }
        sldb[j] = arr * 8192 + cc * 1024;
    }

    // fragment LDS byte offsets: row = t*16 + l16; swizzle = (ks*4+quad)^(l16&7)
    int fro[4][2];
    #pragma unroll
    for (int t = 0; t < 4; ++t)
        #pragma unroll
        for (int ks = 0; ks < 2; ++ks)
            fro[t][ks] = (t * 16 + l16) * 128 + (((ks * 4 + quad) ^ (l16 & 7)) * 16);

    f32x4 oacc[2][4] = {};
    float psum[2][4] = {};

    // prefetch kt = 0 into buffer 0
    #pragma unroll
    for (int j = 0; j < 3; ++j)
        gl16(sp[j] + sofs[j], (char*)KVS[0] + sldb[j]);

    for (int kt = 0; kt < SEQ / 64; ++kt) {
        const int cur = kt & 1;
        __syncthreads();
        if (kt + 1 < SEQ / 64) {
            const int nxt = cur ^ 1;
            #pragma unroll
            for (int j = 0; j < 3; ++j)
                gl16(sp[j] + sofs[j] + (size_t)(kt + 1) * sstep[j], (char*)KVS[nxt] + sldb[j]);
        }

        // ---- S = Q K^T (3-term split) ----
        f32x4 sacc[2][4] = {};   // [sub][t4]
        #pragma unroll
        for (int t4 = 0; t4 < 4; ++t4) {
            bf16x8 kh[2], kl[2];
            #pragma unroll
            for (int ks = 0; ks < 2; ++ks) {
                kh[ks] = *reinterpret_cast<const bf16x8*>((const char*)KVS[cur] + fro[t4][ks]);
                kl[ks] = *reinterpret_cast<const bf16x8*>((const char*)KVS[cur] + 8192 + fro[t4][ks]);
            }
            #pragma unroll
            for (int sub = 0; sub < 2; ++sub) {
                f32x4 a = sacc[sub][t4];
                a = MFMA16(qf[sub][0][0], kh[0], a);
                a = MFMA16(qf[sub][0][0], kl[0], a);
                a = MFMA16(qf[sub][0][1], kh[0], a);
                a = MFMA16(qf[sub][1][0], kh[1], a);
                a = MFMA16(qf[sub][1][0], kl[1], a);
                a = MFMA16(qf[sub][1][1], kh[1], a);
                sacc[sub][t4] = a;
            }
        }

        // ---- p = exp(s/8 - 11.09), truncated to bf16; psum over truncated ----
        #pragma unroll
        for (int sub = 0; sub < 2; ++sub) {
            int rowb = wv * 32 + sub * 16 + quad * 4;
            #pragma unroll
            for (int r = 0; r < 4; ++r) {
                u32 u0 = __float_as_uint(__expf(fmaf(sacc[sub][0][r], 0.125f, -11.0903549f)));
                u32 u1 = __float_as_uint(__expf(fmaf(sacc[sub][1][r], 0.125f, -11.0903549f)));
                u32 u2 = __float_as_uint(__expf(fmaf(sacc[sub][2][r], 0.125f, -11.0903549f)));
                u32 u3 = __float_as_uint(__expf(fmaf(sacc[sub][3][r], 0.125f, -11.0903549f)));
                psum[sub][r] += (__uint_as_float(u0 & 0xffff0000u) + __uint_as_float(u1 & 0xffff0000u))
                              + (__uint_as_float(u2 & 0xffff0000u) + __uint_as_float(u3 & 0xffff0000u));
                int ro = (rowb + r) * 72 + l16;
                Pb[ro +  0] = (u16)(u0 >> 16);
                Pb[ro + 16] = (u16)(u1 >> 16);
                Pb[ro + 32] = (u16)(u2 >> 16);
                Pb[ro + 48] = (u16)(u3 >> 16);
            }
        }
        // Pb rows are wave-private: lgkmcnt ordering only, no barrier.

        // ---- O += P @ V ----
        bf16x8 bvf[4][2];
        #pragma unroll
        for (int dt = 0; dt < 4; ++dt)
            #pragma unroll
            for (int ks = 0; ks < 2; ++ks)
                bvf[dt][ks] = *reinterpret_cast<const bf16x8*>(
                    (const char*)KVS[cur] + 16384 + fro[dt][ks]);
        #pragma unroll
        for (int sub = 0; sub < 2; ++sub) {
            bf16x8 ap[2];
            #pragma unroll
            for (int ks = 0; ks < 2; ++ks)
                ap[ks] = *reinterpret_cast<const bf16x8*>(
                    &Pb[(wv * 32 + sub * 16 + l16) * 72 + ks * 32 + quad * 8]);
            #pragma unroll
            for (int dt = 0; dt < 4; ++dt) {
                oacc[sub][dt] = MFMA16(ap[0], bvf[dt][0], oacc[sub][dt]);
                oacc[sub][dt] = MFMA16(ap[1], bvf[dt][1], oacc[sub][dt]);
            }
        }
    }

    // ---- row-sum reduction across the 16 k-lanes (once) ----
    #pragma unroll
    for (int sub = 0; sub < 2; ++sub)
        #pragma unroll
        for (int r = 0; r < 4; ++r) {
            float s = psum[sub][r];
            s += __shfl_xor(s, 1, 64);
            s += __shfl_xor(s, 2, 64);
            s += __shfl_xor(s, 4, 64);
            s += __shfl_xor(s, 8, 64);
            psum[sub][r] = s;
        }

    // ---- epilogue: normalize, split to hi/lo bf16 ctx ----
    u16* Oh = Ch_g + qbase;
    u16* Ol = Cl_g + qbase;
    #pragma unroll
    for (int sub = 0; sub < 2; ++sub) {
        float inv[4];
        #pragma unroll
        for (int r = 0; r < 4; ++r) inv[r] = 1.0f / psum[sub][r];
        #pragma unroll
        for (int dt = 0; dt < 4; ++dt)
            #pragma unroll
            for (int r = 0; r < 4; ++r) {
                int row = wv * 32 + sub * 16 + quad * 4 + r;
                float v = oacc[sub][dt][r] * inv[r];
                u16 h = f2bf(v);
                size_t idx = (size_t)row * 64 + dt * 16 + l16;
                Oh[idx] = h;
                Ol[idx] = f2bf(v - bf2f(h));
            }
    }
}

// ---------------------------------------------------------------------------
extern "C" void kernel_launch(void* const* d_in, const int* in_sizes, int n_in,
                              void* d_out, int out_size, void* d_ws, size_t ws_size,
                              hipStream_t stream)
{
    const float* x  = (const float*)d_in[0];
    const float* Wq = (const float*)d_in[1];
    const float* bq = (const float*)d_in[2];
    const float* Wk = (const float*)d_in[3];
    const float* bk = (const float*)d_in[4];
    const float* Wv = (const float*)d_in[5];
    const float* bv = (const float*)d_in[6];
    const float* Wo = (const float*)d_in[7];
    const float* bo = (const float*)d_in[8];
    float* out = (float*)d_out;

    const int M = BATCH * SEQ;        // 4096
    const int N = D_MODEL;            // 1024
    const int K = D_MODEL;            // 1024
    const size_t NE = (size_t)M * N;  // 4,194,304
    const size_t NW = (size_t)N * K;  // 1,048,576

    u16* w16 = (u16*)d_ws;
    u16* Xh   = w16;
    u16* Xl   = Xh   + NE;
    u16* Qh   = Xl   + NE;
    u16* Ql   = Qh   + NE;
    u16* Kh   = Ql   + NE;
    u16* Kl   = Kh   + NE;
    u16* Ctxh = Kl   + NE;
    u16* Ctxl = Ctxh + NE;
    u16* Vtb  = Ctxl + NE;
    u16* Vb16 = Vtb  + NE;
    u16* WTqh = Vb16 + NE;
    u16* WTql = WTqh + NW;
    u16* WTkh = WTql + NW;
    u16* WTkl = WTkh + NW;
    u16* WTvh = WTkl + NW;
    u16* WTvl = WTvh + NW;
    u16* WToh = WTvl + NW;
    u16* WTol = WToh + NW;

    // conversions (single launch)
    conv_all<<<dim3(4096 + 1024), dim3(256), 0, stream>>>(
        x, Xh, Xl, (int)(NE / 4),
        Wq, Wk, Wv, Wo, WTqh, WTql, WTkh, WTkl, WTvh, WTvl, WToh, WTol);

    // fused QKV projection (512 threads): Q,K -> hi/lo; V -> flat bf16
    gemm_qkv<<<dim3(N / 128, M / 128), dim3(512), 0, stream>>>(
        Xh, Xl, WTqh, WTql, WTkh, WTkl, WTvh, WTvl,
        bq, bk, bv, Qh, Ql, Kh, Kl, Vb16);

    // transpose V per contiguous reshape slab
    v_transpose<<<dim3(SEQ / 64, BH), dim3(256), 0, stream>>>(Vb16, Vtb);

    // attention (512 threads, 256-q tile) -> ctx hi/lo
    attn_mfma<<<dim3(SEQ / 256, BH), dim3(512), 0, stream>>>(Qh, Ql, Kh, Kl, Vtb, Ctxh, Ctxl);

    // output projection
    gemm_split<<<dim3(N / 128, M / 128), dim3(256), 0, stream>>>(
        Ctxh, Ctxl, WToh, WTol, bo, out, M, N, K);
}

// Round 9
// 241.967 us; speedup vs baseline: 1.3385x; 1.2008x over previous
//
#include <hip/hip_runtime.h>
#include <hip/hip_bf16.h>
#include <math.h>

#define D_MODEL 1024
#define SEQ     2048
#define BATCH   2
#define NHEAD   16
#define DKH     64
#define BH      (BATCH * NHEAD)   // 32

typedef unsigned short u16;
typedef unsigned int   u32;
typedef __bf16 bf16x8 __attribute__((ext_vector_type(8)));
typedef float  f32x4  __attribute__((ext_vector_type(4)));

#define MFMA16(a, b, c) __builtin_amdgcn_mfma_f32_16x16x32_bf16((a), (b), (c), 0, 0, 0)
#define AS1 __attribute__((address_space(1)))
#define AS3 __attribute__((address_space(3)))

__device__ __forceinline__ u16 f2bf(float x) {
    u32 u = __float_as_uint(x);
    u += 0x7fffu + ((u >> 16) & 1u);   // RNE (finite data)
    return (u16)(u >> 16);
}
__device__ __forceinline__ float bf2f(u16 b) {
    return __uint_as_float(((u32)b) << 16);
}
// async global->LDS, 16B/lane; lds dest wave-uniform (lane*16 implicit)
__device__ __forceinline__ void gl16(const u16* g, void* lds) {
    __builtin_amdgcn_global_load_lds((const AS1 u32*)g, (AS3 u32*)lds, 16, 0, 0);
}

// ---------------------------------------------------------------------------
// Conversions, one launch:
//   blocks [0, 4096)    : x fp32 -> bf16 (hi only; 2-term GEMM needs A-hi only)
//   blocks [4096, 5120) : W [K][N] fp32 -> WT hi/lo bf16 [N][K] (4 matrices)
// ---------------------------------------------------------------------------
__global__ __launch_bounds__(256) void conv_all(
    const float* __restrict__ x, u16* __restrict__ Xh, int n4,
    const float* __restrict__ W0, const float* __restrict__ W1,
    const float* __restrict__ W2, const float* __restrict__ W3,
    u16* __restrict__ H0, u16* __restrict__ L0, u16* __restrict__ H1, u16* __restrict__ L1,
    u16* __restrict__ H2, u16* __restrict__ L2, u16* __restrict__ H3, u16* __restrict__ L3)
{
    const int t = threadIdx.x;
    if ((int)blockIdx.x < 4096) {
        int i = blockIdx.x * 256 + t;
        if (i >= n4) return;
        float4 v = reinterpret_cast<const float4*>(x)[i];
        uint2 H;
        H.x = f2bf(v.x) | ((u32)f2bf(v.y) << 16);
        H.y = f2bf(v.z) | ((u32)f2bf(v.w) << 16);
        reinterpret_cast<uint2*>(Xh)[i] = H;
        return;
    }
    int id = blockIdx.x - 4096;          // 0..1023
    int bx = id & 15, by = (id >> 4) & 15, bz = id >> 8;
    const float* W; u16 *Ht, *Lt;
    if (bz == 0)      { W = W0; Ht = H0; Lt = L0; }
    else if (bz == 1) { W = W1; Ht = H1; Lt = L1; }
    else if (bz == 2) { W = W2; Ht = H2; Lt = L2; }
    else              { W = W3; Ht = H3; Lt = L3; }

    __shared__ float T[64][65];
    const int n0 = bx * 64, k0 = by * 64;
    #pragma unroll
    for (int i = 0; i < 4; ++i) {
        int f = t + i * 256;
        int kr = f >> 4, ns = (f & 15) * 4;
        float4 v = *reinterpret_cast<const float4*>(&W[(size_t)(k0 + kr) * D_MODEL + n0 + ns]);
        T[kr][ns + 0] = v.x; T[kr][ns + 1] = v.y; T[kr][ns + 2] = v.z; T[kr][ns + 3] = v.w;
    }
    __syncthreads();
    #pragma unroll
    for (int i = 0; i < 4; ++i) {
        int f = t + i * 256;
        int nr = f >> 4, ks = (f & 15) * 4;
        u16 hh[4], ll[4];
        #pragma unroll
        for (int j = 0; j < 4; ++j) {
            float xv = T[ks + j][nr];
            u16 hb = f2bf(xv);
            hh[j] = hb;
            ll[j] = f2bf(xv - bf2f(hb));
        }
        uint2 H, L;
        H.x = hh[0] | ((u32)hh[1] << 16); H.y = hh[2] | ((u32)hh[3] << 16);
        L.x = ll[0] | ((u32)ll[1] << 16); L.y = ll[2] | ((u32)ll[3] << 16);
        size_t o = (size_t)(n0 + nr) * D_MODEL + k0 + ks;
        *reinterpret_cast<uint2*>(&Ht[o]) = H;
        *reinterpret_cast<uint2*>(&Lt[o]) = L;
    }
}

// ---------------------------------------------------------------------------
// Fused QKV GEMM, 2-term split: C = Ah @ (Bh+Bl)^T + bias.
// 512 threads (8 waves, 2/SIMD); 128x128 tile; wave tile 32x64.
// Staged: Xh + 6 B arrays = 7 x 8 KB/buf; dbuf = 112 KB LDS; prefetch 1.
// 48 MFMA/wave/iter. Outputs Q, K, V all flat bf16.
// ---------------------------------------------------------------------------
__global__ __launch_bounds__(512, 2) void gemm_qkv(
    const u16* __restrict__ AhG,
    const u16* __restrict__ Bqh, const u16* __restrict__ Bql,
    const u16* __restrict__ Bkh, const u16* __restrict__ Bkl,
    const u16* __restrict__ Bvh, const u16* __restrict__ Bvl,
    const float* __restrict__ bq, const float* __restrict__ bk, const float* __restrict__ bv,
    u16* __restrict__ Qb, u16* __restrict__ Kb, u16* __restrict__ Vb)
{
    constexpr int K = D_MODEL, N = D_MODEL;
    __shared__ u16 LB[2][28672];   // per buf: A | Bqh | Bql | Bkh | Bkl | Bvh | Bvl (8KB each)

    const int tid  = threadIdx.x;
    const int wv   = tid >> 6;
    const int lane = tid & 63;
    const int quad = lane >> 4;
    const int l16  = lane & 15;
    const int wm   = wv >> 1, wn = wv & 1;   // 4x2 wave grid, tile 32x64
    const int brow = blockIdx.y * 128, bcol = blockIdx.x * 128;

    // staging: 56 chunks of 1 KB; wave w -> chunks 7w..7w+6
    const u16* sp[7];
    int sldb[7];
    #pragma unroll
    for (int j = 0; j < 7; ++j) {
        int c = wv * 7 + j, a = c >> 3, cc = c & 7;
        int row = cc * 16 + (lane >> 2);
        int gseg = (lane & 3) ^ ((lane >> 3) & 3);
        const u16* p;
        if (a == 0)      p = AhG;
        else if (a == 1) p = Bqh;
        else if (a == 2) p = Bql;
        else if (a == 3) p = Bkh;
        else if (a == 4) p = Bkl;
        else if (a == 5) p = Bvh;
        else             p = Bvl;
        int rbase = (a == 0) ? brow : bcol;
        sp[j]   = p + (size_t)(rbase + row) * K + gseg * 8;
        sldb[j] = a * 8192 + cc * 1024;
    }

    int aro[2], bro[4];
    #pragma unroll
    for (int i = 0; i < 2; ++i) {
        int mr = wm * 32 + i * 16 + l16;
        aro[i] = mr * 64 + ((quad ^ ((mr >> 1) & 3)) * 16);
    }
    #pragma unroll
    for (int i = 0; i < 4; ++i) {
        int nr = wn * 64 + i * 16 + l16;
        bro[i] = nr * 64 + ((quad ^ ((nr >> 1) & 3)) * 16);
    }

    f32x4 acc[3][2][4] = {};

    #pragma unroll
    for (int j = 0; j < 7; ++j)
        gl16(sp[j], (char*)LB[0] + sldb[j]);

    for (int it = 0; it < K / 32; ++it) {
        const int cur = it & 1;
        __syncthreads();
        if (it + 1 < K / 32) {
            const int nxt = cur ^ 1;
            const int k1 = (it + 1) * 32;
            #pragma unroll
            for (int j = 0; j < 7; ++j)
                gl16(sp[j] + k1, (char*)LB[nxt] + sldb[j]);
        }

        bf16x8 ah[2];
        #pragma unroll
        for (int i = 0; i < 2; ++i)
            ah[i] = *reinterpret_cast<const bf16x8*>((const char*)LB[cur] + aro[i]);
        #pragma unroll
        for (int m = 0; m < 3; ++m) {
            const int bbh = (1 + 2 * m) * 8192, bbl = (2 + 2 * m) * 8192;
            bf16x8 bh[4], bl[4];
            #pragma unroll
            for (int i = 0; i < 4; ++i) {
                bh[i] = *reinterpret_cast<const bf16x8*>((const char*)LB[cur] + bbh + bro[i]);
                bl[i] = *reinterpret_cast<const bf16x8*>((const char*)LB[cur] + bbl + bro[i]);
            }
            #pragma unroll
            for (int mi = 0; mi < 2; ++mi)
                #pragma unroll
                for (int ni = 0; ni < 4; ++ni) {
                    f32x4 c = acc[m][mi][ni];
                    c = MFMA16(ah[mi], bh[ni], c);
                    c = MFMA16(ah[mi], bl[ni], c);
                    acc[m][mi][ni] = c;
                }
        }
    }

    // epilogue: all outputs flat bf16
    #pragma unroll
    for (int m = 0; m < 3; ++m) {
        const float* bias = (m == 0) ? bq : (m == 1) ? bk : bv;
        u16* out = (m == 0) ? Qb : (m == 1) ? Kb : Vb;
        #pragma unroll
        for (int mi = 0; mi < 2; ++mi) {
            #pragma unroll
            for (int ni = 0; ni < 4; ++ni) {
                int col = bcol + wn * 64 + ni * 16 + l16;
                float bvv = bias[col];
                #pragma unroll
                for (int r = 0; r < 4; ++r) {
                    int row = brow + wm * 32 + mi * 16 + quad * 4 + r;
                    out[(size_t)row * N + col] = f2bf(acc[m][mi][ni][r] + bvv);
                }
            }
        }
    }
}

// ---------------------------------------------------------------------------
// Out-proj GEMM, 2-term: out = Ctx @ (Woh+Wol)^T + bo, fp32 out.
// 512 threads, wave tile 32x64; staged A|Bh|Bl = 24 KB/buf; 16 MFMA/wave/iter.
// ---------------------------------------------------------------------------
__global__ __launch_bounds__(512, 2) void gemm_oproj(
    const u16* __restrict__ AhG, const u16* __restrict__ Bh, const u16* __restrict__ Bl,
    const float* __restrict__ bias, float* __restrict__ Cf)
{
    constexpr int K = D_MODEL, N = D_MODEL;
    __shared__ u16 LB[2][12288];   // per buf: A | Bh | Bl (8KB each)

    const int tid  = threadIdx.x;
    const int wv   = tid >> 6;
    const int lane = tid & 63;
    const int quad = lane >> 4;
    const int l16  = lane & 15;
    const int wm   = wv >> 1, wn = wv & 1;
    const int brow = blockIdx.y * 128, bcol = blockIdx.x * 128;

    // staging: 24 chunks of 1 KB; wave w -> chunks 3w..3w+2
    const u16* sp[3];
    int sldb[3];
    #pragma unroll
    for (int j = 0; j < 3; ++j) {
        int c = wv * 3 + j, a = c >> 3, cc = c & 7;
        int row = cc * 16 + (lane >> 2);
        int gseg = (lane & 3) ^ ((lane >> 3) & 3);
        const u16* p = (a == 0) ? AhG : (a == 1) ? Bh : Bl;
        int rbase = (a == 0) ? brow : bcol;
        sp[j]   = p + (size_t)(rbase + row) * K + gseg * 8;
        sldb[j] = a * 8192 + cc * 1024;
    }

    int aro[2], bro[4];
    #pragma unroll
    for (int i = 0; i < 2; ++i) {
        int mr = wm * 32 + i * 16 + l16;
        aro[i] = mr * 64 + ((quad ^ ((mr >> 1) & 3)) * 16);
    }
    #pragma unroll
    for (int i = 0; i < 4; ++i) {
        int nr = wn * 64 + i * 16 + l16;
        bro[i] = nr * 64 + ((quad ^ ((nr >> 1) & 3)) * 16);
    }

    f32x4 acc[2][4] = {};

    #pragma unroll
    for (int j = 0; j < 3; ++j)
        gl16(sp[j], (char*)LB[0] + sldb[j]);

    for (int it = 0; it < K / 32; ++it) {
        const int cur = it & 1;
        __syncthreads();
        if (it + 1 < K / 32) {
            const int nxt = cur ^ 1;
            const int k1 = (it + 1) * 32;
            #pragma unroll
            for (int j = 0; j < 3; ++j)
                gl16(sp[j] + k1, (char*)LB[nxt] + sldb[j]);
        }

        bf16x8 ah[2], bh[4], bl[4];
        #pragma unroll
        for (int i = 0; i < 2; ++i)
            ah[i] = *reinterpret_cast<const bf16x8*>((const char*)LB[cur] + aro[i]);
        #pragma unroll
        for (int i = 0; i < 4; ++i) {
            bh[i] = *reinterpret_cast<const bf16x8*>((const char*)LB[cur] + 8192 + bro[i]);
            bl[i] = *reinterpret_cast<const bf16x8*>((const char*)LB[cur] + 16384 + bro[i]);
        }
        #pragma unroll
        for (int mi = 0; mi < 2; ++mi)
            #pragma unroll
            for (int ni = 0; ni < 4; ++ni) {
                f32x4 c = acc[mi][ni];
                c = MFMA16(ah[mi], bh[ni], c);
                c = MFMA16(ah[mi], bl[ni], c);
                acc[mi][ni] = c;
            }
    }

    #pragma unroll
    for (int mi = 0; mi < 2; ++mi) {
        #pragma unroll
        for (int ni = 0; ni < 4; ++ni) {
            int col = bcol + wn * 64 + ni * 16 + l16;
            float bvv = bias[col];
            #pragma unroll
            for (int r = 0; r < 4; ++r) {
                int row = brow + wm * 32 + mi * 16 + quad * 4 + r;
                Cf[(size_t)row * N + col] = acc[mi][ni][r] + bvv;
            }
        }
    }
}

// ---------------------------------------------------------------------------
// V bf16 flat [BH][SEQ][64] (contiguous reshape slabs) -> Vt bf16 [BH][64][SEQ]
// ---------------------------------------------------------------------------
__global__ __launch_bounds__(256) void v_transpose(
    const u16* __restrict__ V, u16* __restrict__ Vt)
{
    __shared__ u16 T[64][72];
    const int bh = blockIdx.y, st = blockIdx.x;
    const u16* src = V + ((size_t)bh * SEQ + (size_t)st * 64) * 64;
    const int t = threadIdx.x;
    #pragma unroll
    for (int i = 0; i < 2; ++i) {
        int c  = t + i * 256;
        int s  = c >> 3;
        int d0 = (c & 7) * 8;
        uint4 v = reinterpret_cast<const uint4*>(src)[c];
        u16 e[8];
        e[0] = (u16)(v.x & 0xffff); e[1] = (u16)(v.x >> 16);
        e[2] = (u16)(v.y & 0xffff); e[3] = (u16)(v.y >> 16);
        e[4] = (u16)(v.z & 0xffff); e[5] = (u16)(v.z >> 16);
        e[6] = (u16)(v.w & 0xffff); e[7] = (u16)(v.w >> 16);
        #pragma unroll
        for (int j = 0; j < 8; ++j) T[d0 + j][s] = e[j];
    }
    __syncthreads();
    const int d = t >> 2, seg = t & 3;
    u16* dst = Vt + (size_t)bh * 64 * SEQ + (size_t)d * SEQ + st * 64 + seg * 16;
    uint4 a = *reinterpret_cast<const uint4*>(&T[d][seg * 16]);
    uint4 b = *reinterpret_cast<const uint4*>(&T[d][seg * 16 + 8]);
    reinterpret_cast<uint4*>(dst)[0] = a;
    reinterpret_cast<uint4*>(dst)[1] = b;
}

// ---------------------------------------------------------------------------
// MFMA flash attention: plain-bf16 QK^T (Qb,Kb single), bf16 PV, no-max
// softmax with truncated-P sum. 512 threads, 256-q tile, 32 q-rows/wave.
// 1D grid, XCD swizzle: bh = id&31 (all q-tiles of a head on one XCD).
// LDS: (Kh|Vt) 2 x 16 KB + Pb 36 KB = 68 KB. 32 MFMA/wave/iter.
// ---------------------------------------------------------------------------
__global__ __launch_bounds__(512, 2) void attn_mfma(
    const u16* __restrict__ Qb_g, const u16* __restrict__ Kb_g,
    const u16* __restrict__ Vt_g, u16* __restrict__ Ch_g)
{
    __shared__ u16 KVS[2][8192];   // per buf: Kb(8KB) | Vt(8KB)
    __shared__ u16 Pb [256 * 72];

    const int tid  = threadIdx.x;
    const int wv   = tid >> 6;
    const int lane = tid & 63;
    const int quad = lane >> 4;
    const int l16  = lane & 15;
    const int id   = blockIdx.x;
    const int bh   = id & 31;       // XCD = id%8 = bh%8: K/V L2-local per XCD
    const int qt   = id >> 5;

    const size_t qbase = ((size_t)bh * SEQ + (size_t)qt * 256) * 64;
    const size_t kbh   = (size_t)bh * SEQ * 64;
    const size_t vtbh  = (size_t)bh * 64 * SEQ;

    // ---- Q fragments: direct global -> VGPR (32 q-rows per wave) ----
    bf16x8 qf[2][2];   // [sub][ks]
    #pragma unroll
    for (int sub = 0; sub < 2; ++sub)
        #pragma unroll
        for (int ks = 0; ks < 2; ++ks) {
            size_t o = qbase + (size_t)(wv * 32 + sub * 16 + l16) * 64 + ks * 32 + quad * 8;
            qf[sub][ks] = *reinterpret_cast<const bf16x8*>(Qb_g + o);
        }

    // K/V staging: 16 chunks of 1 KB (Kb 0-7, Vt 8-15); 2 per wave
    const u16* sp[2];
    size_t sstep[2];
    int sldb[2];
    #pragma unroll
    for (int j = 0; j < 2; ++j) {
        int c   = wv * 2 + j;
        int arr = c >> 3, cc = c & 7;
        int row = cc * 8 + (lane >> 3);
        int sg  = (lane & 7) ^ (row & 7);
        if (arr == 0) { sp[j] = Kb_g + kbh + (size_t)row * 64 + sg * 8;   sstep[j] = 4096; }
        else          { sp[j] = Vt_g + vtbh + (size_t)row * SEQ + sg * 8; sstep[j] = 64; }
        sldb[j] = arr * 8192 + cc * 1024;
    }

    int fro[4][2];
    #pragma unroll
    for (int t = 0; t < 4; ++t)
        #pragma unroll
        for (int ks = 0; ks < 2; ++ks)
            fro[t][ks] = (t * 16 + l16) * 128 + (((ks * 4 + quad) ^ (l16 & 7)) * 16);

    f32x4 oacc[2][4] = {};
    float psum[2][4] = {};

    #pragma unroll
    for (int j = 0; j < 2; ++j)
        gl16(sp[j], (char*)KVS[0] + sldb[j]);

    for (int kt = 0; kt < SEQ / 64; ++kt) {
        const int cur = kt & 1;
        __syncthreads();
        if (kt + 1 < SEQ / 64) {
            const int nxt = cur ^ 1;
            #pragma unroll
            for (int j = 0; j < 2; ++j)
                gl16(sp[j] + (size_t)(kt + 1) * sstep[j], (char*)KVS[nxt] + sldb[j]);
        }

        // ---- S = Q K^T (plain bf16) ----
        f32x4 sacc[2][4] = {};
        #pragma unroll
        for (int t4 = 0; t4 < 4; ++t4) {
            bf16x8 kh[2];
            kh[0] = *reinterpret_cast<const bf16x8*>((const char*)KVS[cur] + fro[t4][0]);
            kh[1] = *reinterpret_cast<const bf16x8*>((const char*)KVS[cur] + fro[t4][1]);
            #pragma unroll
            for (int sub = 0; sub < 2; ++sub) {
                f32x4 a = sacc[sub][t4];
                a = MFMA16(qf[sub][0], kh[0], a);
                a = MFMA16(qf[sub][1], kh[1], a);
                sacc[sub][t4] = a;
            }
        }

        // ---- p = 2^(s*0.18034 - 16) (== exp(s/8 - 16 ln2)), truncated bf16;
        //      psum over truncated values cancels truncation bias exactly ----
        #pragma unroll
        for (int sub = 0; sub < 2; ++sub) {
            int rowb = wv * 32 + sub * 16 + quad * 4;
            #pragma unroll
            for (int r = 0; r < 4; ++r) {
                u32 u0 = __float_as_uint(exp2f(fmaf(sacc[sub][0][r], 0.18033688f, -16.0f)));
                u32 u1 = __float_as_uint(exp2f(fmaf(sacc[sub][1][r], 0.18033688f, -16.0f)));
                u32 u2 = __float_as_uint(exp2f(fmaf(sacc[sub][2][r], 0.18033688f, -16.0f)));
                u32 u3 = __float_as_uint(exp2f(fmaf(sacc[sub][3][r], 0.18033688f, -16.0f)));
                psum[sub][r] += (__uint_as_float(u0 & 0xffff0000u) + __uint_as_float(u1 & 0xffff0000u))
                              + (__uint_as_float(u2 & 0xffff0000u) + __uint_as_float(u3 & 0xffff0000u));
                int ro = (rowb + r) * 72 + l16;
                Pb[ro +  0] = (u16)(u0 >> 16);
                Pb[ro + 16] = (u16)(u1 >> 16);
                Pb[ro + 32] = (u16)(u2 >> 16);
                Pb[ro + 48] = (u16)(u3 >> 16);
            }
        }
        // Pb rows are wave-private: lgkmcnt ordering only, no barrier.

        // ---- O += P @ V ----
        bf16x8 bvf[4][2];
        #pragma unroll
        for (int dt = 0; dt < 4; ++dt) {
            bvf[dt][0] = *reinterpret_cast<const bf16x8*>((const char*)KVS[cur] + 8192 + fro[dt][0]);
            bvf[dt][1] = *reinterpret_cast<const bf16x8*>((const char*)KVS[cur] + 8192 + fro[dt][1]);
        }
        #pragma unroll
        for (int sub = 0; sub < 2; ++sub) {
            bf16x8 ap[2];
            #pragma unroll
            for (int ks = 0; ks < 2; ++ks)
                ap[ks] = *reinterpret_cast<const bf16x8*>(
                    &Pb[(wv * 32 + sub * 16 + l16) * 72 + ks * 32 + quad * 8]);
            #pragma unroll
            for (int dt = 0; dt < 4; ++dt) {
                oacc[sub][dt] = MFMA16(ap[0], bvf[dt][0], oacc[sub][dt]);
                oacc[sub][dt] = MFMA16(ap[1], bvf[dt][1], oacc[sub][dt]);
            }
        }
    }

    // ---- row-sum across the 16 k-lanes ----
    #pragma unroll
    for (int sub = 0; sub < 2; ++sub)
        #pragma unroll
        for (int r = 0; r < 4; ++r) {
            float s = psum[sub][r];
            s += __shfl_xor(s, 1, 64);
            s += __shfl_xor(s, 2, 64);
            s += __shfl_xor(s, 4, 64);
            s += __shfl_xor(s, 8, 64);
            psum[sub][r] = s;
        }

    // ---- epilogue: normalize, store ctx bf16 (single) ----
    u16* Oh = Ch_g + qbase;
    #pragma unroll
    for (int sub = 0; sub < 2; ++sub) {
        float inv[4];
        #pragma unroll
        for (int r = 0; r < 4; ++r) inv[r] = 1.0f / psum[sub][r];
        #pragma unroll
        for (int dt = 0; dt < 4; ++dt)
            #pragma unroll
            for (int r = 0; r < 4; ++r) {
                int row = wv * 32 + sub * 16 + quad * 4 + r;
                Oh[(size_t)row * 64 + dt * 16 + l16] = f2bf(oacc[sub][dt][r] * inv[r]);
            }
    }
}

// ---------------------------------------------------------------------------
extern "C" void kernel_launch(void* const* d_in, const int* in_sizes, int n_in,
                              void* d_out, int out_size, void* d_ws, size_t ws_size,
                              hipStream_t stream)
{
    const float* x  = (const float*)d_in[0];
    const float* Wq = (const float*)d_in[1];
    const float* bq = (const float*)d_in[2];
    const float* Wk = (const float*)d_in[3];
    const float* bk = (const float*)d_in[4];
    const float* Wv = (const float*)d_in[5];
    const float* bv = (const float*)d_in[6];
    const float* Wo = (const float*)d_in[7];
    const float* bo = (const float*)d_in[8];
    float* out = (float*)d_out;

    const int M = BATCH * SEQ;        // 4096
    const int N = D_MODEL;            // 1024
    const size_t NE = (size_t)M * N;  // 4,194,304
    const size_t NW = (size_t)N * N;  // 1,048,576

    u16* w16 = (u16*)d_ws;
    u16* Xh   = w16;
    u16* Qb   = Xh   + NE;
    u16* Kb   = Qb   + NE;
    u16* Vb   = Kb   + NE;
    u16* Vtb  = Vb   + NE;
    u16* Ctxh = Vtb  + NE;
    u16* WTqh = Ctxh + NE;
    u16* WTql = WTqh + NW;
    u16* WTkh = WTql + NW;
    u16* WTkl = WTkh + NW;
    u16* WTvh = WTkl + NW;
    u16* WTvl = WTvh + NW;
    u16* WToh = WTvl + NW;
    u16* WTol = WToh + NW;

    // conversions (single launch)
    conv_all<<<dim3(4096 + 1024), dim3(256), 0, stream>>>(
        x, Xh, (int)(NE / 4),
        Wq, Wk, Wv, Wo, WTqh, WTql, WTkh, WTkl, WTvh, WTvl, WToh, WTol);

    // fused QKV projection (2-term, 512 threads): Q,K,V flat bf16
    gemm_qkv<<<dim3(N / 128, M / 128), dim3(512), 0, stream>>>(
        Xh, WTqh, WTql, WTkh, WTkl, WTvh, WTvl, bq, bk, bv, Qb, Kb, Vb);

    // transpose V per contiguous reshape slab
    v_transpose<<<dim3(SEQ / 64, BH), dim3(256), 0, stream>>>(Vb, Vtb);

    // attention (plain-bf16 QK^T, XCD-swizzled 1D grid) -> ctx bf16
    attn_mfma<<<dim3((SEQ / 256) * BH), dim3(512), 0, stream>>>(Qb, Kb, Vtb, Ctxh);

    // output projection (2-term, 512 threads)
    gemm_oproj<<<dim3(N / 128, M / 128), dim3(512), 0, stream>>>(
        Ctxh, WToh, WTol, bo, out);
}

// Round 10
// 223.544 us; speedup vs baseline: 1.4488x; 1.0824x over previous
//
#include <hip/hip_runtime.h>
#include <hip/hip_bf16.h>
#include <math.h>

#define D_MODEL 1024
#define SEQ     2048
#define BATCH   2
#define NHEAD   16
#define DKH     64
#define BH      (BATCH * NHEAD)   // 32

typedef unsigned short u16;
typedef unsigned int   u32;
typedef __bf16 bf16x8 __attribute__((ext_vector_type(8)));
typedef float  f32x4  __attribute__((ext_vector_type(4)));

#define MFMA16(a, b, c) __builtin_amdgcn_mfma_f32_16x16x32_bf16((a), (b), (c), 0, 0, 0)
#define AS1 __attribute__((address_space(1)))
#define AS3 __attribute__((address_space(3)))

// 1/(8*ln2): folded into Q so softmax is exp2(s) with no fma and no shift
#define QSCALE 0.18033688f

__device__ __forceinline__ u16 f2bf(float x) {
    u32 u = __float_as_uint(x);
    u += 0x7fffu + ((u >> 16) & 1u);   // RNE (finite data)
    return (u16)(u >> 16);
}
__device__ __forceinline__ float bf2f(u16 b) {
    return __uint_as_float(((u32)b) << 16);
}
// async global->LDS, 16B/lane; lds dest wave-uniform (lane*16 implicit)
__device__ __forceinline__ void gl16(const u16* g, void* lds) {
    __builtin_amdgcn_global_load_lds((const AS1 u32*)g, (AS3 u32*)lds, 16, 0, 0);
}

// ---------------------------------------------------------------------------
// Conversions, one launch:
//   blocks [0, 4096)    : x fp32 -> bf16 (hi only)
//   blocks [4096, 5120) : W [K][N] fp32 -> WT hi/lo bf16 [N][K] (4 matrices)
// ---------------------------------------------------------------------------
__global__ __launch_bounds__(256) void conv_all(
    const float* __restrict__ x, u16* __restrict__ Xh, int n4,
    const float* __restrict__ W0, const float* __restrict__ W1,
    const float* __restrict__ W2, const float* __restrict__ W3,
    u16* __restrict__ H0, u16* __restrict__ L0, u16* __restrict__ H1, u16* __restrict__ L1,
    u16* __restrict__ H2, u16* __restrict__ L2, u16* __restrict__ H3, u16* __restrict__ L3)
{
    const int t = threadIdx.x;
    if ((int)blockIdx.x < 4096) {
        int i = blockIdx.x * 256 + t;
        if (i >= n4) return;
        float4 v = reinterpret_cast<const float4*>(x)[i];
        uint2 H;
        H.x = f2bf(v.x) | ((u32)f2bf(v.y) << 16);
        H.y = f2bf(v.z) | ((u32)f2bf(v.w) << 16);
        reinterpret_cast<uint2*>(Xh)[i] = H;
        return;
    }
    int id = blockIdx.x - 4096;          // 0..1023
    int bx = id & 15, by = (id >> 4) & 15, bz = id >> 8;
    const float* W; u16 *Ht, *Lt;
    if (bz == 0)      { W = W0; Ht = H0; Lt = L0; }
    else if (bz == 1) { W = W1; Ht = H1; Lt = L1; }
    else if (bz == 2) { W = W2; Ht = H2; Lt = L2; }
    else              { W = W3; Ht = H3; Lt = L3; }

    __shared__ float T[64][65];
    const int n0 = bx * 64, k0 = by * 64;
    #pragma unroll
    for (int i = 0; i < 4; ++i) {
        int f = t + i * 256;
        int kr = f >> 4, ns = (f & 15) * 4;
        float4 v = *reinterpret_cast<const float4*>(&W[(size_t)(k0 + kr) * D_MODEL + n0 + ns]);
        T[kr][ns + 0] = v.x; T[kr][ns + 1] = v.y; T[kr][ns + 2] = v.z; T[kr][ns + 3] = v.w;
    }
    __syncthreads();
    #pragma unroll
    for (int i = 0; i < 4; ++i) {
        int f = t + i * 256;
        int nr = f >> 4, ks = (f & 15) * 4;
        u16 hh[4], ll[4];
        #pragma unroll
        for (int j = 0; j < 4; ++j) {
            float xv = T[ks + j][nr];
            u16 hb = f2bf(xv);
            hh[j] = hb;
            ll[j] = f2bf(xv - bf2f(hb));
        }
        uint2 H, L;
        H.x = hh[0] | ((u32)hh[1] << 16); H.y = hh[2] | ((u32)hh[3] << 16);
        L.x = ll[0] | ((u32)ll[1] << 16); L.y = ll[2] | ((u32)ll[3] << 16);
        size_t o = (size_t)(n0 + nr) * D_MODEL + k0 + ks;
        *reinterpret_cast<uint2*>(&Ht[o]) = H;
        *reinterpret_cast<uint2*>(&Lt[o]) = L;
    }
}

// ---------------------------------------------------------------------------
// Fused QKV GEMM, 2-term split: C = Ah @ (Bh+Bl)^T + bias.
// 512 threads (8 waves, 2/SIMD); 128x128 tile; wave tile 32x64.
// Q output pre-scaled by QSCALE (softmax fold). All outputs flat bf16.
// ---------------------------------------------------------------------------
__global__ __launch_bounds__(512, 2) void gemm_qkv(
    const u16* __restrict__ AhG,
    const u16* __restrict__ Bqh, const u16* __restrict__ Bql,
    const u16* __restrict__ Bkh, const u16* __restrict__ Bkl,
    const u16* __restrict__ Bvh, const u16* __restrict__ Bvl,
    const float* __restrict__ bq, const float* __restrict__ bk, const float* __restrict__ bv,
    u16* __restrict__ Qb, u16* __restrict__ Kb, u16* __restrict__ Vb)
{
    constexpr int K = D_MODEL, N = D_MODEL;
    __shared__ u16 LB[2][28672];   // per buf: A | Bqh | Bql | Bkh | Bkl | Bvh | Bvl (8KB each)

    const int tid  = threadIdx.x;
    const int wv   = tid >> 6;
    const int lane = tid & 63;
    const int quad = lane >> 4;
    const int l16  = lane & 15;
    const int wm   = wv >> 1, wn = wv & 1;
    const int brow = blockIdx.y * 128, bcol = blockIdx.x * 128;

    const u16* sp[7];
    int sldb[7];
    #pragma unroll
    for (int j = 0; j < 7; ++j) {
        int c = wv * 7 + j, a = c >> 3, cc = c & 7;
        int row = cc * 16 + (lane >> 2);
        int gseg = (lane & 3) ^ ((lane >> 3) & 3);
        const u16* p;
        if (a == 0)      p = AhG;
        else if (a == 1) p = Bqh;
        else if (a == 2) p = Bql;
        else if (a == 3) p = Bkh;
        else if (a == 4) p = Bkl;
        else if (a == 5) p = Bvh;
        else             p = Bvl;
        int rbase = (a == 0) ? brow : bcol;
        sp[j]   = p + (size_t)(rbase + row) * K + gseg * 8;
        sldb[j] = a * 8192 + cc * 1024;
    }

    int aro[2], bro[4];
    #pragma unroll
    for (int i = 0; i < 2; ++i) {
        int mr = wm * 32 + i * 16 + l16;
        aro[i] = mr * 64 + ((quad ^ ((mr >> 1) & 3)) * 16);
    }
    #pragma unroll
    for (int i = 0; i < 4; ++i) {
        int nr = wn * 64 + i * 16 + l16;
        bro[i] = nr * 64 + ((quad ^ ((nr >> 1) & 3)) * 16);
    }

    f32x4 acc[3][2][4] = {};

    #pragma unroll
    for (int j = 0; j < 7; ++j)
        gl16(sp[j], (char*)LB[0] + sldb[j]);

    for (int it = 0; it < K / 32; ++it) {
        const int cur = it & 1;
        __syncthreads();
        if (it + 1 < K / 32) {
            const int nxt = cur ^ 1;
            const int k1 = (it + 1) * 32;
            #pragma unroll
            for (int j = 0; j < 7; ++j)
                gl16(sp[j] + k1, (char*)LB[nxt] + sldb[j]);
        }

        bf16x8 ah[2];
        #pragma unroll
        for (int i = 0; i < 2; ++i)
            ah[i] = *reinterpret_cast<const bf16x8*>((const char*)LB[cur] + aro[i]);
        #pragma unroll
        for (int m = 0; m < 3; ++m) {
            const int bbh = (1 + 2 * m) * 8192, bbl = (2 + 2 * m) * 8192;
            bf16x8 bh[4], bl[4];
            #pragma unroll
            for (int i = 0; i < 4; ++i) {
                bh[i] = *reinterpret_cast<const bf16x8*>((const char*)LB[cur] + bbh + bro[i]);
                bl[i] = *reinterpret_cast<const bf16x8*>((const char*)LB[cur] + bbl + bro[i]);
            }
            #pragma unroll
            for (int mi = 0; mi < 2; ++mi)
                #pragma unroll
                for (int ni = 0; ni < 4; ++ni) {
                    f32x4 c = acc[m][mi][ni];
                    c = MFMA16(ah[mi], bh[ni], c);
                    c = MFMA16(ah[mi], bl[ni], c);
                    acc[m][mi][ni] = c;
                }
        }
    }

    // epilogue: Q pre-scaled for exp2-softmax; all flat bf16
    #pragma unroll
    for (int m = 0; m < 3; ++m) {
        const float* bias = (m == 0) ? bq : (m == 1) ? bk : bv;
        u16* out = (m == 0) ? Qb : (m == 1) ? Kb : Vb;
        const float sc = (m == 0) ? QSCALE : 1.0f;
        #pragma unroll
        for (int mi = 0; mi < 2; ++mi) {
            #pragma unroll
            for (int ni = 0; ni < 4; ++ni) {
                int col = bcol + wn * 64 + ni * 16 + l16;
                float bvv = bias[col];
                #pragma unroll
                for (int r = 0; r < 4; ++r) {
                    int row = brow + wm * 32 + mi * 16 + quad * 4 + r;
                    out[(size_t)row * N + col] = f2bf((acc[m][mi][ni][r] + bvv) * sc);
                }
            }
        }
    }
}

// ---------------------------------------------------------------------------
// Out-proj GEMM, 2-term: out = Ctx @ (Woh+Wol)^T + bo, fp32 out.
// ---------------------------------------------------------------------------
__global__ __launch_bounds__(512, 2) void gemm_oproj(
    const u16* __restrict__ AhG, const u16* __restrict__ Bh, const u16* __restrict__ Bl,
    const float* __restrict__ bias, float* __restrict__ Cf)
{
    constexpr int K = D_MODEL, N = D_MODEL;
    __shared__ u16 LB[2][12288];   // per buf: A | Bh | Bl (8KB each)

    const int tid  = threadIdx.x;
    const int wv   = tid >> 6;
    const int lane = tid & 63;
    const int quad = lane >> 4;
    const int l16  = lane & 15;
    const int wm   = wv >> 1, wn = wv & 1;
    const int brow = blockIdx.y * 128, bcol = blockIdx.x * 128;

    const u16* sp[3];
    int sldb[3];
    #pragma unroll
    for (int j = 0; j < 3; ++j) {
        int c = wv * 3 + j, a = c >> 3, cc = c & 7;
        int row = cc * 16 + (lane >> 2);
        int gseg = (lane & 3) ^ ((lane >> 3) & 3);
        const u16* p = (a == 0) ? AhG : (a == 1) ? Bh : Bl;
        int rbase = (a == 0) ? brow : bcol;
        sp[j]   = p + (size_t)(rbase + row) * K + gseg * 8;
        sldb[j] = a * 8192 + cc * 1024;
    }

    int aro[2], bro[4];
    #pragma unroll
    for (int i = 0; i < 2; ++i) {
        int mr = wm * 32 + i * 16 + l16;
        aro[i] = mr * 64 + ((quad ^ ((mr >> 1) & 3)) * 16);
    }
    #pragma unroll
    for (int i = 0; i < 4; ++i) {
        int nr = wn * 64 + i * 16 + l16;
        bro[i] = nr * 64 + ((quad ^ ((nr >> 1) & 3)) * 16);
    }

    f32x4 acc[2][4] = {};

    #pragma unroll
    for (int j = 0; j < 3; ++j)
        gl16(sp[j], (char*)LB[0] + sldb[j]);

    for (int it = 0; it < K / 32; ++it) {
        const int cur = it & 1;
        __syncthreads();
        if (it + 1 < K / 32) {
            const int nxt = cur ^ 1;
            const int k1 = (it + 1) * 32;
            #pragma unroll
            for (int j = 0; j < 3; ++j)
                gl16(sp[j] + k1, (char*)LB[nxt] + sldb[j]);
        }

        bf16x8 ah[2], bh[4], bl[4];
        #pragma unroll
        for (int i = 0; i < 2; ++i)
            ah[i] = *reinterpret_cast<const bf16x8*>((const char*)LB[cur] + aro[i]);
        #pragma unroll
        for (int i = 0; i < 4; ++i) {
            bh[i] = *reinterpret_cast<const bf16x8*>((const char*)LB[cur] + 8192 + bro[i]);
            bl[i] = *reinterpret_cast<const bf16x8*>((const char*)LB[cur] + 16384 + bro[i]);
        }
        #pragma unroll
        for (int mi = 0; mi < 2; ++mi)
            #pragma unroll
            for (int ni = 0; ni < 4; ++ni) {
                f32x4 c = acc[mi][ni];
                c = MFMA16(ah[mi], bh[ni], c);
                c = MFMA16(ah[mi], bl[ni], c);
                acc[mi][ni] = c;
            }
    }

    #pragma unroll
    for (int mi = 0; mi < 2; ++mi) {
        #pragma unroll
        for (int ni = 0; ni < 4; ++ni) {
            int col = bcol + wn * 64 + ni * 16 + l16;
            float bvv = bias[col];
            #pragma unroll
            for (int r = 0; r < 4; ++r) {
                int row = brow + wm * 32 + mi * 16 + quad * 4 + r;
                Cf[(size_t)row * N + col] = acc[mi][ni][r] + bvv;
            }
        }
    }
}

// ---------------------------------------------------------------------------
// V bf16 flat [BH][SEQ][64] -> Vt bf16 [BH][64][SEQ]
// ---------------------------------------------------------------------------
__global__ __launch_bounds__(256) void v_transpose(
    const u16* __restrict__ V, u16* __restrict__ Vt)
{
    __shared__ u16 T[64][72];
    const int bh = blockIdx.y, st = blockIdx.x;
    const u16* src = V + ((size_t)bh * SEQ + (size_t)st * 64) * 64;
    const int t = threadIdx.x;
    #pragma unroll
    for (int i = 0; i < 2; ++i) {
        int c  = t + i * 256;
        int s  = c >> 3;
        int d0 = (c & 7) * 8;
        uint4 v = reinterpret_cast<const uint4*>(src)[c];
        u16 e[8];
        e[0] = (u16)(v.x & 0xffff); e[1] = (u16)(v.x >> 16);
        e[2] = (u16)(v.y & 0xffff); e[3] = (u16)(v.y >> 16);
        e[4] = (u16)(v.z & 0xffff); e[5] = (u16)(v.z >> 16);
        e[6] = (u16)(v.w & 0xffff); e[7] = (u16)(v.w >> 16);
        #pragma unroll
        for (int j = 0; j < 8; ++j) T[d0 + j][s] = e[j];
    }
    __syncthreads();
    const int d = t >> 2, seg = t & 3;
    u16* dst = Vt + (size_t)bh * 64 * SEQ + (size_t)d * SEQ + st * 64 + seg * 16;
    uint4 a = *reinterpret_cast<const uint4*>(&T[d][seg * 16]);
    uint4 b = *reinterpret_cast<const uint4*>(&T[d][seg * 16 + 8]);
    reinterpret_cast<uint4*>(dst)[0] = a;
    reinterpret_cast<uint4*>(dst)[1] = b;
}

// ---------------------------------------------------------------------------
// MFMA flash attention: Q pre-scaled -> p = exp2(s) raw (no fma, no shift);
// truncated-bf16 P; row sums via ones-MFMA on the SAME bf16 P fragments
// (denominator == numerator weights exactly; no shuffles, no psum VALU).
// 256 threads, 128-q tile, 32 q-rows/wave; LDS 50 KB -> 2 blocks/CU.
// 1D grid (512), XCD swizzle bh = id&31.
// ---------------------------------------------------------------------------
__global__ __launch_bounds__(256, 2) void attn_mfma(
    const u16* __restrict__ Qb_g, const u16* __restrict__ Kb_g,
    const u16* __restrict__ Vt_g, u16* __restrict__ Ch_g)
{
    __shared__ u16 KVS[2][8192];   // per buf: Kb(8KB) | Vt(8KB)
    __shared__ u16 Pb [128 * 72];

    const int tid  = threadIdx.x;
    const int wv   = tid >> 6;          // 0..3
    const int lane = tid & 63;
    const int quad = lane >> 4;
    const int l16  = lane & 15;
    const int id   = blockIdx.x;
    const int bh   = id & 31;           // XCD = id%8 = bh%8
    const int qt   = id >> 5;           // 0..15

    const size_t qbase = ((size_t)bh * SEQ + (size_t)qt * 128) * 64;
    const size_t kbh   = (size_t)bh * SEQ * 64;
    const size_t vtbh  = (size_t)bh * 64 * SEQ;

    // ---- Q fragments: direct global -> VGPR (32 q-rows per wave) ----
    bf16x8 qf[2][2];
    #pragma unroll
    for (int sub = 0; sub < 2; ++sub)
        #pragma unroll
        for (int ks = 0; ks < 2; ++ks) {
            size_t o = qbase + (size_t)(wv * 32 + sub * 16 + l16) * 64 + ks * 32 + quad * 8;
            qf[sub][ks] = *reinterpret_cast<const bf16x8*>(Qb_g + o);
        }

    // K/V staging: 16 chunks of 1 KB (Kb 0-7, Vt 8-15); 4 per wave
    const u16* sp[4];
    size_t sstep[4];
    int sldb[4];
    #pragma unroll
    for (int j = 0; j < 4; ++j) {
        int c   = wv * 4 + j;            // 0..15
        int arr = c >> 3, cc = c & 7;
        int row = cc * 8 + (lane >> 3);
        int sg  = (lane & 7) ^ (row & 7);
        if (arr == 0) { sp[j] = Kb_g + kbh + (size_t)row * 64 + sg * 8;   sstep[j] = 4096; }
        else          { sp[j] = Vt_g + vtbh + (size_t)row * SEQ + sg * 8; sstep[j] = 64; }
        sldb[j] = arr * 8192 + cc * 1024;
    }

    int fro[4][2];
    #pragma unroll
    for (int t = 0; t < 4; ++t)
        #pragma unroll
        for (int ks = 0; ks < 2; ++ks)
            fro[t][ks] = (t * 16 + l16) * 128 + (((ks * 4 + quad) ^ (l16 & 7)) * 16);

    bf16x8 onesv;
    #pragma unroll
    for (int i = 0; i < 8; ++i) onesv[i] = (__bf16)1.0f;

    f32x4 oacc[2][4] = {};
    f32x4 lsum[2] = {};

    #pragma unroll
    for (int j = 0; j < 4; ++j)
        gl16(sp[j], (char*)KVS[0] + sldb[j]);

    for (int kt = 0; kt < SEQ / 64; ++kt) {
        const int cur = kt & 1;
        __syncthreads();
        if (kt + 1 < SEQ / 64) {
            const int nxt = cur ^ 1;
            #pragma unroll
            for (int j = 0; j < 4; ++j)
                gl16(sp[j] + (size_t)(kt + 1) * sstep[j], (char*)KVS[nxt] + sldb[j]);
        }

        // ---- S = Q K^T (plain bf16; Q pre-scaled) ----
        f32x4 sacc[2][4] = {};
        #pragma unroll
        for (int t4 = 0; t4 < 4; ++t4) {
            bf16x8 kh[2];
            kh[0] = *reinterpret_cast<const bf16x8*>((const char*)KVS[cur] + fro[t4][0]);
            kh[1] = *reinterpret_cast<const bf16x8*>((const char*)KVS[cur] + fro[t4][1]);
            #pragma unroll
            for (int sub = 0; sub < 2; ++sub) {
                f32x4 a = sacc[sub][t4];
                a = MFMA16(qf[sub][0], kh[0], a);
                a = MFMA16(qf[sub][1], kh[1], a);
                sacc[sub][t4] = a;
            }
        }

        // ---- p = exp2(s), truncate to bf16, store to Pb (wave-private) ----
        #pragma unroll
        for (int sub = 0; sub < 2; ++sub) {
            int rowb = wv * 32 + sub * 16 + quad * 4;
            #pragma unroll
            for (int r = 0; r < 4; ++r) {
                u32 u0 = __float_as_uint(__builtin_amdgcn_exp2f(sacc[sub][0][r]));
                u32 u1 = __float_as_uint(__builtin_amdgcn_exp2f(sacc[sub][1][r]));
                u32 u2 = __float_as_uint(__builtin_amdgcn_exp2f(sacc[sub][2][r]));
                u32 u3 = __float_as_uint(__builtin_amdgcn_exp2f(sacc[sub][3][r]));
                int ro = (rowb + r) * 72 + l16;
                Pb[ro +  0] = (u16)(u0 >> 16);
                Pb[ro + 16] = (u16)(u1 >> 16);
                Pb[ro + 32] = (u16)(u2 >> 16);
                Pb[ro + 48] = (u16)(u3 >> 16);
            }
        }

        // ---- O += P @ V ; lsum += P @ 1 (exact same bf16 P fragments) ----
        bf16x8 bvf[4][2];
        #pragma unroll
        for (int dt = 0; dt < 4; ++dt) {
            bvf[dt][0] = *reinterpret_cast<const bf16x8*>((const char*)KVS[cur] + 8192 + fro[dt][0]);
            bvf[dt][1] = *reinterpret_cast<const bf16x8*>((const char*)KVS[cur] + 8192 + fro[dt][1]);
        }
        #pragma unroll
        for (int sub = 0; sub < 2; ++sub) {
            bf16x8 ap[2];
            #pragma unroll
            for (int ks = 0; ks < 2; ++ks)
                ap[ks] = *reinterpret_cast<const bf16x8*>(
                    &Pb[(wv * 32 + sub * 16 + l16) * 72 + ks * 32 + quad * 8]);
            #pragma unroll
            for (int dt = 0; dt < 4; ++dt) {
                oacc[sub][dt] = MFMA16(ap[0], bvf[dt][0], oacc[sub][dt]);
                oacc[sub][dt] = MFMA16(ap[1], bvf[dt][1], oacc[sub][dt]);
            }
            lsum[sub] = MFMA16(ap[0], onesv, lsum[sub]);
            lsum[sub] = MFMA16(ap[1], onesv, lsum[sub]);
        }
    }

    // ---- epilogue: normalize by lsum (C-layout rows match oacc), store ----
    u16* Oh = Ch_g + qbase;
    #pragma unroll
    for (int sub = 0; sub < 2; ++sub) {
        float inv[4];
        #pragma unroll
        for (int r = 0; r < 4; ++r) inv[r] = 1.0f / lsum[sub][r];
        #pragma unroll
        for (int dt = 0; dt < 4; ++dt)
            #pragma unroll
            for (int r = 0; r < 4; ++r) {
                int row = wv * 32 + sub * 16 + quad * 4 + r;
                Oh[(size_t)row * 64 + dt * 16 + l16] = f2bf(oacc[sub][dt][r] * inv[r]);
            }
    }
}

// ---------------------------------------------------------------------------
extern "C" void kernel_launch(void* const* d_in, const int* in_sizes, int n_in,
                              void* d_out, int out_size, void* d_ws, size_t ws_size,
                              hipStream_t stream)
{
    const float* x  = (const float*)d_in[0];
    const float* Wq = (const float*)d_in[1];
    const float* bq = (const float*)d_in[2];
    const float* Wk = (const float*)d_in[3];
    const float* bk = (const float*)d_in[4];
    const float* Wv = (const float*)d_in[5];
    const float* bv = (const float*)d_in[6];
    const float* Wo = (const float*)d_in[7];
    const float* bo = (const float*)d_in[8];
    float* out = (float*)d_out;

    const int M = BATCH * SEQ;        // 4096
    const int N = D_MODEL;            // 1024
    const size_t NE = (size_t)M * N;  // 4,194,304
    const size_t NW = (size_t)N * N;  // 1,048,576

    u16* w16 = (u16*)d_ws;
    u16* Xh   = w16;
    u16* Qb   = Xh   + NE;
    u16* Kb   = Qb   + NE;
    u16* Vb   = Kb   + NE;
    u16* Vtb  = Vb   + NE;
    u16* Ctxh = Vtb  + NE;
    u16* WTqh = Ctxh + NE;
    u16* WTql = WTqh + NW;
    u16* WTkh = WTql + NW;
    u16* WTkl = WTkh + NW;
    u16* WTvh = WTkl + NW;
    u16* WTvl = WTvh + NW;
    u16* WToh = WTvl + NW;
    u16* WTol = WToh + NW;

    // conversions (single launch)
    conv_all<<<dim3(4096 + 1024), dim3(256), 0, stream>>>(
        x, Xh, (int)(NE / 4),
        Wq, Wk, Wv, Wo, WTqh, WTql, WTkh, WTkl, WTvh, WTvl, WToh, WTol);

    // fused QKV projection (2-term, 512 threads): Q pre-scaled; flat bf16
    gemm_qkv<<<dim3(N / 128, M / 128), dim3(512), 0, stream>>>(
        Xh, WTqh, WTql, WTkh, WTkl, WTvh, WTvl, bq, bk, bv, Qb, Kb, Vb);

    // transpose V per contiguous reshape slab
    v_transpose<<<dim3(SEQ / 64, BH), dim3(256), 0, stream>>>(Vb, Vtb);

    // attention (exp2 softmax, ones-MFMA row sums, 2 blocks/CU)
    attn_mfma<<<dim3((SEQ / 128) * BH), dim3(256), 0, stream>>>(Qb, Kb, Vtb, Ctxh);

    // output projection (2-term, 512 threads)
    gemm_oproj<<<dim3(N / 128, M / 128), dim3(512), 0, stream>>>(
        Ctxh, WToh, WTol, bo, out);
}